// Round 7
// baseline (14430.252 us; speedup 1.0000x reference)
//
#include <hip/hip_runtime.h>
#include <hip/hip_bf16.h>

typedef __hip_bfloat16 bf16;
typedef short bf8v __attribute__((ext_vector_type(8)));   // 8 x bf16 (4 VGPR)
typedef float f32x4 __attribute__((ext_vector_type(4)));

#define DEVINL __device__ __forceinline__
#define MFMA16(a, b, c) __builtin_amdgcn_mfma_f32_16x16x32_bf16((a), (b), (c), 0, 0, 0)

DEVINL float us2f(unsigned short u) { unsigned v = ((unsigned)u) << 16; return __uint_as_float(v); }
DEVINL float b2f(bf16 x) { return __bfloat162float(x); }
DEVINL bf16 f2b(float x) { return __float2bfloat16(x); }
DEVINL float sigf(float x) { return 1.0f / (1.0f + expf(-x)); }
DEVINL unsigned short f2bu(float f) { bf16 h = __float2bfloat16(f); return *(unsigned short*)&h; }

DEVINL void gload16(const void* g, void* l) {
  __builtin_amdgcn_global_load_lds((const __attribute__((address_space(1))) void*)g,
                                   (__attribute__((address_space(3))) void*)l, 16, 0, 0);
}

// ---- relaxed agent-scope atomics ----
DEVINL unsigned ald(const unsigned* p) {
  return __hip_atomic_load(p, __ATOMIC_RELAXED, __HIP_MEMORY_SCOPE_AGENT);
}
DEVINL void ast(unsigned* p, unsigned v) {
  __hip_atomic_store(p, v, __ATOMIC_RELAXED, __HIP_MEMORY_SCOPE_AGENT);
}
DEVINL float aldf(const float* p) { unsigned u = ald((const unsigned*)p); return __uint_as_float(u); }
DEVINL void astf(float* p, float v) { ast((unsigned*)p, __float_as_uint(v)); }

// ---- global 256-block barrier (8 groups x 32), parity-buffered ----
DEVINL void gridbar2(unsigned* bars, unsigned lgen) {
  __syncthreads();
  if (threadIdx.x == 0) {
    unsigned s = lgen & 1;
    unsigned g = blockIdx.x >> 5;
    unsigned* grp = bars + (g * 2 + s) * 16;
    unsigned* top = bars + (16 + s) * 16;
    unsigned* gen = bars + 288;
    unsigned t = __hip_atomic_fetch_add(grp, 1u, __ATOMIC_RELAXED, __HIP_MEMORY_SCOPE_AGENT);
    if (t == 31u) {
      ast(grp, 0u);
      unsigned tt = __hip_atomic_fetch_add(top, 1u, __ATOMIC_RELAXED, __HIP_MEMORY_SCOPE_AGENT);
      if (tt == 7u) {
        ast(top, 0u);
        asm volatile("s_waitcnt vmcnt(0)");
        ast(gen, lgen + 1u);
      }
    }
    while (ald(gen) <= lgen) __builtin_amdgcn_s_sleep(4);
  }
  __syncthreads();
}

// ---- local 64-block barrier (2 groups x 32) ----
DEVINL void bar64(unsigned* b, unsigned lgen, int lid) {
  __syncthreads();
  if (threadIdx.x == 0) {
    unsigned s = lgen & 1;
    unsigned* grp = b + (((unsigned)(lid >> 5) & 1u) * 2 + s) * 16;
    unsigned* top = b + (4 + s) * 16;
    unsigned* gen = b + 96;
    unsigned t = __hip_atomic_fetch_add(grp, 1u, __ATOMIC_RELAXED, __HIP_MEMORY_SCOPE_AGENT);
    if (t == 31u) {
      ast(grp, 0u);
      unsigned tt = __hip_atomic_fetch_add(top, 1u, __ATOMIC_RELAXED, __HIP_MEMORY_SCOPE_AGENT);
      if (tt == 1u) {
        ast(top, 0u);
        asm volatile("s_waitcnt vmcnt(0)");
        ast(gen, lgen + 1u);
      }
    }
    while (ald(gen) <= lgen) __builtin_amdgcn_s_sleep(2);
  }
  __syncthreads();
}

// ---------------- ws layout (bytes); total <= 272,629,760 ----
#define OKPT_H  ((size_t)0)
#define OKPT_L  ((size_t)8388608)
#define ORPT_H  ((size_t)16777216)
#define ORPT_L  ((size_t)25165824)
#define OXE_H   ((size_t)35651584)
#define OXE_L   ((size_t)69206016)
#define OHSF5   ((size_t)35651584)
#define XCH     ((size_t)136314880)
#define OHPK_E0 (XCH + 0)
#define OHPK_E1 (XCH + 262144)
#define OHPK_D0 (XCH + 524288)
#define OCBUF5  (XCH + 1048576)
#define OAHPK   (XCH + 1310720)
#define ORSUM5  (XCH + 1572864)
#define ORMAX5  (XCH + 1638400)
#define ORIDX5  (XCH + 1769472)
#define OPSUM5  (XCH + 1900544)
#define OBARS5  (XCH + 1901568)
#define OXK_L5  ((size_t)138412032)
#define OWCT_H  ((size_t)0)
#define OWCT_L  ((size_t)4194304)
#define OPCTX5  ((size_t)8388608)
#define OQBUF   ORPT_H              /* 64*1024*4 = 256KB over dead RpT */
#define OWOT5   ((size_t)138412032)
#define OKRTH5  ((size_t)203948032)
#define OKRTL5  ((size_t)220725248)

#define DELTA   1e-4f

// decoder LDS pool offsets (pool 150528)
#define D_LH   0
#define D_LL   32768
#define D_ZS   65536
#define D_KBH  83968
#define D_KBL  116736
#define D4_A   0
#define D4_W   16384
#define D4_E   49152
#define D_QL   0
#define D_PSC  4096
#define D_EK   8448
#define D_PC4  8704
#define D_ZS3  0
#define D_PSC2 0
#define D_GMX  4352
#define D_CCN  8512
#define D_CAND 8576
#define D_YL   149504
#define D_INV  149568
#define D_RT   149632

// ---------------- utility kernels ----------------
__global__ void ed_zero_v7(float4* p, int n) {
  int i = blockIdx.x * 256 + threadIdx.x;
  if (i < n) p[i] = make_float4(0.f, 0.f, 0.f, 0.f);
}

__global__ void ed_transpose_v7(const float* __restrict__ in, bf16* __restrict__ out,
                                int R, int C, int ostride, int ooff, int perm) {
  __shared__ float tile[32][33];
  int c0 = blockIdx.x * 32, r0 = blockIdx.y * 32;
  int tx = threadIdx.x & 31, ty0 = threadIdx.x >> 5;
#pragma unroll
  for (int i = 0; i < 4; i++) {
    int ty = ty0 + i * 8;
    tile[ty][tx] = in[(size_t)(r0 + ty) * C + c0 + tx];
  }
  __syncthreads();
#pragma unroll
  for (int i = 0; i < 4; i++) {
    int ty = ty0 + i * 8;
    int c = c0 + ty;
    int oc = perm ? ((c & 1023) * 4 + (c >> 10)) : c;
    out[(size_t)oc * ostride + ooff + r0 + tx] = f2b(tile[tx][ty]);
  }
}

__global__ void ed_transpose_split_v7(const float* __restrict__ in, bf16* __restrict__ oh,
                                      bf16* __restrict__ ol, int R, int C, int ostride,
                                      int ooff, int perm) {
  __shared__ float tile[32][33];
  int c0 = blockIdx.x * 32, r0 = blockIdx.y * 32;
  int tx = threadIdx.x & 31, ty0 = threadIdx.x >> 5;
#pragma unroll
  for (int i = 0; i < 4; i++) {
    int ty = ty0 + i * 8;
    tile[ty][tx] = in[(size_t)(r0 + ty) * C + c0 + tx];
  }
  __syncthreads();
#pragma unroll
  for (int i = 0; i < 4; i++) {
    int ty = ty0 + i * 8;
    int c = c0 + ty;
    int oc = perm ? ((c & 1023) * 4 + (c >> 10)) : c;
    float v = tile[tx][ty];
    bf16 hh = f2b(v);
    size_t o = (size_t)oc * ostride + ooff + r0 + tx;
    oh[o] = hh;
    ol[o] = f2b(v - b2f(hh));
  }
}

__global__ void ed_gather_split_v7(const int* __restrict__ src, const float* __restrict__ emb,
                                   bf16* __restrict__ xh, bf16* __restrict__ xl) {
  int bid = blockIdx.x;
  int t = bid >> 6, b = bid & 63;
  int tok = src[b * 256 + t];
  const float* rowp = emb + (size_t)tok * 1024;
  int i = threadIdx.x * 4;
  float4 v = *(const float4*)(rowp + i);
  bf16 h0 = f2b(v.x), h1 = f2b(v.y), h2 = f2b(v.z), h3 = f2b(v.w);
  ushort4 oh, ol;
  oh.x = *(unsigned short*)&h0; oh.y = *(unsigned short*)&h1;
  oh.z = *(unsigned short*)&h2; oh.w = *(unsigned short*)&h3;
  ol.x = f2bu(v.x - b2f(h0)); ol.y = f2bu(v.y - b2f(h1));
  ol.z = f2bu(v.z - b2f(h2)); ol.w = f2bu(v.w - b2f(h3));
  *(ushort4*)(xh + (size_t)bid * 1024 + i) = oh;
  *(ushort4*)(xl + (size_t)bid * 1024 + i) = ol;
}

// ---------------- split-precision GEMM (3-term), split output (Xk) ----------------
__global__ __launch_bounds__(256, 2) void ed_gemm3_v7(
    const bf16* __restrict__ Ah, const bf16* __restrict__ Al,
    const bf16* __restrict__ Bh, const bf16* __restrict__ Bl,
    bf16* __restrict__ Ch, bf16* __restrict__ Cl, int M, int N, int K) {
  __shared__ __align__(16) bf16 Ash[128 * 32];
  __shared__ __align__(16) bf16 Asl[128 * 32];
  __shared__ __align__(16) bf16 Bsh[128 * 32];
  __shared__ __align__(16) bf16 Bsl[128 * 32];
  int m0 = blockIdx.y * 128, n0 = blockIdx.x * 128;
  int tid = threadIdx.x, w = tid >> 6, l = tid & 63;
  int wm = w >> 1, wn = w & 1;
  int lr = l & 15, lq = l >> 4;
  f32x4 acc[4][4] = {};
  for (int k0 = 0; k0 < K; k0 += 32) {
    __syncthreads();
#pragma unroll
    for (int j = 0; j < 2; j++) {
      int o = (w * 2 + j) * 1024 + l * 16;
      int rrow = o >> 6, kk = (o & 63) >> 1;
      gload16(Ah + (size_t)(m0 + rrow) * K + k0 + kk, (char*)Ash + (w * 2 + j) * 1024);
      gload16(Al + (size_t)(m0 + rrow) * K + k0 + kk, (char*)Asl + (w * 2 + j) * 1024);
      gload16(Bh + (size_t)(n0 + rrow) * K + k0 + kk, (char*)Bsh + (w * 2 + j) * 1024);
      gload16(Bl + (size_t)(n0 + rrow) * K + k0 + kk, (char*)Bsl + (w * 2 + j) * 1024);
    }
    __syncthreads();
#pragma unroll
    for (int mi = 0; mi < 4; mi++) {
      bf8v a_h = *(const bf8v*)(Ash + (wm * 64 + mi * 16 + lr) * 32 + lq * 8);
      bf8v a_l = *(const bf8v*)(Asl + (wm * 64 + mi * 16 + lr) * 32 + lq * 8);
#pragma unroll
      for (int ni = 0; ni < 4; ni++) {
        bf8v b_h = *(const bf8v*)(Bsh + (wn * 64 + ni * 16 + lr) * 32 + lq * 8);
        bf8v b_l = *(const bf8v*)(Bsl + (wn * 64 + ni * 16 + lr) * 32 + lq * 8);
        acc[mi][ni] = MFMA16(a_h, b_h, acc[mi][ni]);
        acc[mi][ni] = MFMA16(a_h, b_l, acc[mi][ni]);
        acc[mi][ni] = MFMA16(a_l, b_h, acc[mi][ni]);
      }
    }
  }
#pragma unroll
  for (int mi = 0; mi < 4; mi++)
#pragma unroll
    for (int ni = 0; ni < 4; ni++)
#pragma unroll
      for (int r = 0; r < 4; r++) {
        float v = acc[mi][ni][r];
        bf16 hh = f2b(v);
        size_t idx = (size_t)(m0 + wm * 64 + mi * 16 + lq * 4 + r) * N + n0 + wn * 64 + ni * 16 + lr;
        Ch[idx] = hh;
        Cl[idx] = f2b(v - b2f(hh));
      }
}

// ---------------- encoder: per-bg local barriers; hsf cached (no NT) ----------------
__global__ __launch_bounds__(1024, 4) void ed_enc_v7(
    const int* __restrict__ src, const bf16* __restrict__ Rh, const bf16* __restrict__ Rl,
    const bf16* __restrict__ Xh, const bf16* __restrict__ Xl, const float* __restrict__ enc_b,
    unsigned* hpk0, unsigned* hpk1, float* __restrict__ cbuf,
    float* __restrict__ hsf, unsigned* barsE) {
  extern __shared__ char sm[];
  bf16* lh = (bf16*)sm;
  bf16* ll = (bf16*)(sm + 32768);
  float* zs = (float*)(sm + 65536);
  float* xkf = (float*)(sm + 82944);
  int bid = blockIdx.x, tid = threadIdx.x;
  int bg = bid >> 6, cg = bid & 63, lid = bid & 63;
  unsigned* barL = barsE + bg * 128;
  int wv = tid >> 6, l = tid & 63, lr = l & 15, lq = l >> 4;
  int kq = wv >> 2, cs = wv & 3;
  int srow = tid >> 6, sj0 = (tid & 63) * 16;
  int grow = tid >> 4, gul = tid & 15;
  bf8v Rh_[8], Rl_[8];
  {
    const bf16* bh = Rh + (size_t)(cg * 64 + cs * 16 + lr) * 1024 + kq * 256 + lq * 8;
    const bf16* bl = Rl + (size_t)(cg * 64 + cs * 16 + lr) * 1024 + kq * 256 + lq * 8;
#pragma unroll
    for (int i = 0; i < 8; i++) {
      Rh_[i] = *(const bf8v*)(bh + i * 32);
      Rl_[i] = *(const bf8v*)(bl + i * 32);
    }
  }
  float bi[4];
  float c_ = 0.f;
  if (tid < 256) {
#pragma unroll
    for (int g = 0; g < 4; g++) {
      int colp = cg * 64 + gul * 4 + g;
      bi[g] = enc_b[(colp & 3) * 1024 + (colp >> 2)];
    }
  }
  unsigned *hc = hpk0, *hn = hpk1;
  unsigned lgen = 0;
  for (int t = 0; t < 256; t++) {
    {
      const unsigned* hrow = hc + (size_t)(bg * 16 + srow) * 1024 + sj0;
      unsigned u[16];
#pragma unroll
      for (int j = 0; j < 16; j++) u[j] = ald(hrow + j);
      int r8 = (srow & 7) << 3;
#pragma unroll
      for (int j = 0; j < 16; j += 2) {
        int es = (sj0 + j) ^ r8;
        *(unsigned*)((char*)lh + srow * 2048 + es * 2) = (u[j] >> 16) | (u[j + 1] & 0xffff0000u);
        *(unsigned*)((char*)ll + srow * 2048 + es * 2) = (u[j] & 0xffffu) | (u[j + 1] << 16);
      }
    }
    {
      int xr = tid >> 6, xc = tid & 63;
      size_t xi = ((size_t)t * 64 + bg * 16 + xr) * 4096 + cg * 64 + xc;
      unsigned short xh = __builtin_nontemporal_load((const unsigned short*)(Xh + xi));
      unsigned short xl = __builtin_nontemporal_load((const unsigned short*)(Xl + xi));
      xkf[xr * 64 + xc] = us2f(xh) + us2f(xl);
    }
    __syncthreads();
    {
      f32x4 acc = {0.f, 0.f, 0.f, 0.f};
      int r8 = (lr & 7) << 3;
#pragma unroll
      for (int i = 0; i < 8; i++) {
        int e0 = kq * 256 + i * 32 + lq * 8;
        int es = e0 ^ r8;
        bf8v a_h = *(const bf8v*)((char*)lh + lr * 2048 + es * 2);
        bf8v a_l = *(const bf8v*)((char*)ll + lr * 2048 + es * 2);
        acc = MFMA16(a_h, Rh_[i], acc);
        acc = MFMA16(a_h, Rl_[i], acc);
        acc = MFMA16(a_l, Rh_[i], acc);
        acc = MFMA16(a_l, Rl_[i], acc);
      }
#pragma unroll
      for (int r = 0; r < 4; r++) zs[(kq * 16 + lq * 4 + r) * 68 + cs * 16 + lr] = acc[r];
    }
    __syncthreads();
    if (tid < 256) {
      int b_ = bg * 16 + grow, u = cg * 16 + gul;
      float zz[4];
#pragma unroll
      for (int g = 0; g < 4; g++) {
        int cc = gul * 4 + g;
        zz[g] = zs[(0 + grow) * 68 + cc] + zs[(16 + grow) * 68 + cc] +
                zs[(32 + grow) * 68 + cc] + zs[(48 + grow) * 68 + cc] +
                xkf[grow * 64 + cc] + bi[g];
      }
      float iv = sigf(zz[0]), fv = sigf(zz[1]), gv = tanhf(zz[2]), ov = sigf(zz[3]);
      float cn = fv * c_ + iv * gv;
      float hnv = ov * tanhf(cn);
      bool m = src[b_ * 256 + t] > 0;
      int es = u ^ ((grow & 7) << 3);
      float hold = b2f(*(const bf16*)((char*)lh + grow * 2048 + es * 2)) +
                   b2f(*(const bf16*)((char*)ll + grow * 2048 + es * 2));
      float hv = m ? hnv : hold;
      c_ = m ? cn : c_;
      unsigned short uh = f2bu(hv);
      unsigned pkv = ((unsigned)uh << 16) | (unsigned)f2bu(hv - us2f(uh));
      ast(hn + (size_t)b_ * 1024 + u, pkv);
      hsf[((size_t)t * 64 + b_) * 1024 + u] = hv;
    }
    bar64(barL, lgen, lid);
    lgen++;
    unsigned* tp = hc; hc = hn; hn = tp;
  }
  if (tid < 256) cbuf[(size_t)(bg * 16 + grow) * 1024 + cg * 16 + gul] = c_;
}

// ---------------- decoder LSTM (chunked KRT staging via gload16) ----------------
DEVINL void dec_lstm7(int bg, int cgl, int tid, char* sm,
                      const unsigned* hc, unsigned* hn,
                      const float* __restrict__ dec_emb,
                      const bf16* __restrict__ Kh, const bf16* __restrict__ Kl,
                      const float* __restrict__ dec_b, float& c_) {
  bf16* lh = (bf16*)(sm + D_LH);
  bf16* ll = (bf16*)(sm + D_LL);
  {
    int srow = tid >> 6, sl = tid & 63;
    const unsigned* hrow = hc + (size_t)(bg * 16 + srow) * 1024 + sl * 16;
    unsigned u[16];
#pragma unroll
    for (int j = 0; j < 16; j++) u[j] = ald(hrow + j);
    uint4 ha, hb, la, lb;
    ha.x = (u[0] >> 16) | (u[1] & 0xffff0000u);  ha.y = (u[2] >> 16) | (u[3] & 0xffff0000u);
    ha.z = (u[4] >> 16) | (u[5] & 0xffff0000u);  ha.w = (u[6] >> 16) | (u[7] & 0xffff0000u);
    hb.x = (u[8] >> 16) | (u[9] & 0xffff0000u);  hb.y = (u[10] >> 16) | (u[11] & 0xffff0000u);
    hb.z = (u[12] >> 16) | (u[13] & 0xffff0000u); hb.w = (u[14] >> 16) | (u[15] & 0xffff0000u);
    la.x = (u[0] & 0xffffu) | (u[1] << 16);  la.y = (u[2] & 0xffffu) | (u[3] << 16);
    la.z = (u[4] & 0xffffu) | (u[5] << 16);  la.w = (u[6] & 0xffffu) | (u[7] << 16);
    lb.x = (u[8] & 0xffffu) | (u[9] << 16);  lb.y = (u[10] & 0xffffu) | (u[11] << 16);
    lb.z = (u[12] & 0xffffu) | (u[13] << 16); lb.w = (u[14] & 0xffffu) | (u[15] << 16);
    int swz = (srow & 7) << 4;
    char* rbh = (char*)lh + srow * 2048;
    char* rbl = (char*)ll + srow * 2048;
    *(uint4*)(rbh + ((sl * 32) ^ swz)) = ha;
    *(uint4*)(rbh + ((sl * 32 + 16) ^ swz)) = hb;
    *(uint4*)(rbl + ((sl * 32) ^ swz)) = la;
    *(uint4*)(rbl + ((sl * 32 + 16) ^ swz)) = lb;
  }
  int wv = tid >> 6, l = tid & 63, lr = l & 15, lq = l >> 4;
  int kg2 = wv >> 2, cs = wv & 3;
  bf16* kbh = (bf16*)(sm + D_KBH);
  bf16* kbl = (bf16*)(sm + D_KBL);
  const int* y_l = (const int*)(sm + D_YL);
  float* zs = (float*)(sm + D_ZS);
  f32x4 acc = {0.f, 0.f, 0.f, 0.f};
  int colB = cs * 16 + lr;
  int bswz = (colB & 7) << 4;
  int aswz = (lr & 7) << 4;
  for (int c = 0; c < 8; c++) {
    __syncthreads();
#pragma unroll
    for (int r = 0; r < 2; r++) {
      int i = wv * 128 + r * 64 + l;
      int col = i >> 5, j = i & 31;
      size_t se = (size_t)(cgl * 64 + col) * 2048 + c * 256 + ((size_t)(j ^ (col & 7)) << 3);
      gload16(Kh + se, (char*)kbh + wv * 2048 + r * 1024);
      gload16(Kl + se, (char*)kbl + wv * 2048 + r * 1024);
    }
    __syncthreads();
#pragma unroll
    for (int s = 0; s < 2; s++) {
      int kl = kg2 * 64 + s * 32 + lq * 8;
      bf8v b_h = *(const bf8v*)((char*)kbh + colB * 512 + ((kl * 2) ^ bswz));
      bf8v b_l = *(const bf8v*)((char*)kbl + colB * 512 + ((kl * 2) ^ bswz));
      int gk = c * 256 + kl;
      bf8v a_h, a_l;
      if (gk < 1024) {
        const float* xr = dec_emb + (size_t)y_l[lr] * 1024 + gk;
        float4 v0 = *(const float4*)xr;
        float4 v1 = *(const float4*)(xr + 4);
        float vs[8] = {v0.x, v0.y, v0.z, v0.w, v1.x, v1.y, v1.z, v1.w};
#pragma unroll
        for (int e = 0; e < 8; e++) {
          unsigned short uh = f2bu(vs[e]);
          a_h[e] = (short)uh;
          a_l[e] = (short)f2bu(vs[e] - us2f(uh));
        }
      } else {
        int hk = gk - 1024;
        a_h = *(const bf8v*)((char*)lh + lr * 2048 + ((hk * 2) ^ aswz));
        a_l = *(const bf8v*)((char*)ll + lr * 2048 + ((hk * 2) ^ aswz));
      }
      acc = MFMA16(a_h, b_h, acc);
      acc = MFMA16(a_h, b_l, acc);
      acc = MFMA16(a_l, b_h, acc);
      acc = MFMA16(a_l, b_l, acc);
    }
  }
#pragma unroll
  for (int r = 0; r < 4; r++) zs[(kg2 * 16 + lq * 4 + r) * 68 + cs * 16 + lr] = acc[r];
  __syncthreads();
  if (tid < 256) {
    int grow = tid >> 4, gul = tid & 15;
    int b_ = bg * 16 + grow;
    float zz[4];
#pragma unroll
    for (int g = 0; g < 4; g++) {
      int cc = gul * 4 + g;
      int colp = cgl * 64 + cc;
      float v = zs[(0 + grow) * 68 + cc] + zs[(16 + grow) * 68 + cc] +
                zs[(32 + grow) * 68 + cc] + zs[(48 + grow) * 68 + cc];
      zz[g] = v + dec_b[(colp & 3) * 1024 + (colp >> 2)];
    }
    float iv = sigf(zz[0]), fv = sigf(zz[1]), gv = tanhf(zz[2]), ov = sigf(zz[3]);
    float cn = fv * c_ + iv * gv;
    c_ = cn;
    float hv = ov * tanhf(cn);
    unsigned short uh = f2bu(hv);
    unsigned pkv = ((unsigned)uh << 16) | (unsigned)f2bu(hv - us2f(uh));
    ast(hn + (size_t)b_ * 1024 + cgl * 16 + gul, pkv);
  }
}

// ---------------- decoder persistent kernel ----------------
__global__ __launch_bounds__(1024, 4) void ed_dec_v7(
    const int* __restrict__ src,
    const bf16* __restrict__ KRh, const bf16* __restrict__ KRl, const float* __restrict__ dec_b,
    const bf16* __restrict__ WcTh, const bf16* __restrict__ WcTl, const float* __restrict__ b_cp,
    const bf16* __restrict__ WoTh, const float* __restrict__ b_op,
    const float* __restrict__ Wout_f32, const float* __restrict__ dec_emb,
    const float* __restrict__ W_a, float* __restrict__ qbuf,
    const float* __restrict__ hsf,
    unsigned* hpkA, unsigned* hpkB, float* __restrict__ cbuf,
    float* __restrict__ pctx, float* __restrict__ psum, unsigned* ahpk,
    float* __restrict__ rowsum, float* __restrict__ rmax, int* __restrict__ ridx,
    float* __restrict__ out, unsigned* barsG, unsigned* barsL) {
  extern __shared__ char sm[];
  int bid = blockIdx.x, tid = threadIdx.x;
  int bg = bid >> 6, cgl = bid & 63, lid = bid & 63;
  unsigned* barL = barsL + bg * 128;
  int wv = tid >> 6, l = tid & 63, lr = l & 15, lq = l >> 4;
  float c_ = 0.f;
  if (tid < 256) c_ = cbuf[(size_t)(bg * 16 + (tid >> 4)) * 1024 + cgl * 16 + (tid & 15)];
  unsigned *hc = hpkA, *hn = hpkB;
  unsigned lgenL = 0, lgenG = 0;

  if (tid < 16) ((int*)(sm + D_YL))[tid] = 1;
  __syncthreads();
  dec_lstm7(bg, cgl, tid, sm, hc, hn, dec_emb, KRh, KRl, dec_b, c_);
  bar64(barL, lgenL, lid); lgenL++;
  { unsigned* tp = hc; hc = hn; hn = tp; }

  for (int st = 0; st < 32; st++) {
    // ---- PQ: q[b] = W_a @ h[b] for this bg's 16 rows; active blocks cgl<16 ----
    if (cgl < 16) {
      int colb = cgl * 64;
      int kq = wv >> 2, nq = wv & 3;
      float* zs = (float*)(sm + D_ZS);
      f32x4 acc = {0.f, 0.f, 0.f, 0.f};
      const unsigned* hrow = hc + (size_t)(bg * 16 + lr) * 1024;
      const float* warow = W_a + (size_t)(colb + nq * 16 + lr) * 1024;
#pragma unroll
      for (int i = 0; i < 8; i++) {
        int k = kq * 256 + i * 32 + lq * 8;
        bf8v a, b;
        const unsigned* hp = hrow + k;
#pragma unroll
        for (int e = 0; e < 8; e++) a[e] = (short)(ald(hp + e) >> 16);
        const float* wp = warow + k;
        float4 w0 = *(const float4*)wp;
        float4 w1 = *(const float4*)(wp + 4);
        b[0] = (short)f2bu(w0.x); b[1] = (short)f2bu(w0.y);
        b[2] = (short)f2bu(w0.z); b[3] = (short)f2bu(w0.w);
        b[4] = (short)f2bu(w1.x); b[5] = (short)f2bu(w1.y);
        b[6] = (short)f2bu(w1.z); b[7] = (short)f2bu(w1.w);
        acc = MFMA16(a, b, acc);
      }
#pragma unroll
      for (int r = 0; r < 4; r++) zs[(kq * 16 + lq * 4 + r) * 68 + nq * 16 + lr] = acc[r];
      __syncthreads();
      {
        int mrow = tid >> 6, col = tid & 63;
        float v = zs[(0 + mrow) * 68 + col] + zs[(16 + mrow) * 68 + col] +
                  zs[(32 + mrow) * 68 + col] + zs[(48 + mrow) * 68 + col];
        astf(qbuf + (size_t)(bg * 16 + mrow) * 1024 + colb + col, v);
      }
    }
    bar64(barL, lgenL, lid); lgenL++;
    // ---- P1: scores = hsf·q + exp + partial ctx; block = (b, kg) ----
    {
      int b_ = bid >> 2, kg = bid & 3;
      float* q_l = (float*)(sm + D_QL);
      q_l[tid] = aldf(qbuf + (size_t)b_ * 1024 + tid);
      __syncthreads();
      float* psc = (float*)(sm + D_PSC);
      {
        int kl = tid >> 4, qq = tid & 15;
        const float* hrow = hsf + ((size_t)(kg * 64 + kl) * 64 + b_) * 1024;
        float p = 0.f;
#pragma unroll 4
        for (int j = 0; j < 16; j++) {
          int e0 = j * 64 + qq * 4;
          float4 hv = *(const float4*)(hrow + e0);
          p += hv.x * q_l[e0] + hv.y * q_l[e0 + 1] + hv.z * q_l[e0 + 2] + hv.w * q_l[e0 + 3];
        }
        psc[kl * 17 + qq] = p;
      }
      __syncthreads();
      float* ek = (float*)(sm + D_EK);
      if (tid < 64) {
        float sc = 0.f;
#pragma unroll
        for (int q = 0; q < 16; q++) sc += psc[tid * 17 + q];
        ek[tid] = (src[b_ * 256 + kg * 64 + tid] > 0) ? expf(sc) : 0.f;
      }
      __syncthreads();
      float* pc4 = (float*)(sm + D_PC4);
      {
        int cq = tid & 255, kc = tid >> 8;
        float a0 = 0.f, a1 = 0.f, a2 = 0.f, a3 = 0.f;
#pragma unroll 4
        for (int j = 0; j < 16; j++) {
          float e = ek[kc * 16 + j];
          const float* hr = hsf + ((size_t)(kg * 64 + kc * 16 + j) * 64 + b_) * 1024 + cq * 4;
          float4 uv = *(const float4*)hr;
          a0 += e * uv.x; a1 += e * uv.y; a2 += e * uv.z; a3 += e * uv.w;
        }
        pc4[kc * 1024 + cq * 4 + 0] = a0;
        pc4[kc * 1024 + cq * 4 + 1] = a1;
        pc4[kc * 1024 + cq * 4 + 2] = a2;
        pc4[kc * 1024 + cq * 4 + 3] = a3;
      }
      __syncthreads();
      {
        float v = pc4[tid] + pc4[1024 + tid] + pc4[2048 + tid] + pc4[3072 + tid];
        astf(pctx + ((size_t)kg * 64 + b_) * 1024 + tid, v);
      }
      if (tid == 0) {
        float* ek2 = (float*)(sm + D_EK);
        float s_ = 0.f;
        for (int i2 = 0; i2 < 64; i2++) s_ += ek2[i2];
        astf(psum + kg * 64 + b_, s_);
      }
    }
    bar64(barL, lgenL, lid); lgenL++;
    // ---- P3: ctx-reduce + ah = tanh([ctx,h]@W_c + b_c); block = (bg, 16-col) ----
    {
      float* inv_l = (float*)(sm + D_INV);
      if (tid < 16) {
        int rb = bg * 16 + tid;
        float sg = aldf(psum + rb) + aldf(psum + 64 + rb) +
                   aldf(psum + 128 + rb) + aldf(psum + 192 + rb);
        inv_l[tid] = 1.0f / sg;
      }
      __syncthreads();
      float* zs3 = (float*)(sm + D_ZS3);
      {
        int kq = wv;
        f32x4 acc = {0.f, 0.f, 0.f, 0.f};
        const bf16* bh = WcTh + (size_t)(cgl * 16 + lr) * 2048;
        const bf16* bl = WcTl + (size_t)(cgl * 16 + lr) * 2048;
        float inv = inv_l[lr];
#pragma unroll
        for (int i = 0; i < 4; i++) {
          int k = kq * 128 + i * 32 + lq * 8;
          bf8v a_h, a_l;
          if (k < 1024) {
            const float* p0 = pctx + (size_t)(bg * 16 + lr) * 1024 + k;
#pragma unroll
            for (int e = 0; e < 8; e++) {
              float v = (aldf(p0 + e) + aldf(p0 + 65536 + e) +
                         aldf(p0 + 131072 + e) + aldf(p0 + 196608 + e)) * inv;
              unsigned short uh = f2bu(v);
              a_h[e] = (short)uh;
              a_l[e] = (short)f2bu(v - us2f(uh));
            }
          } else {
            const unsigned* hp = hc + (size_t)(bg * 16 + lr) * 1024 + (k - 1024);
#pragma unroll
            for (int e = 0; e < 8; e++) {
              unsigned u = ald(hp + e);
              a_h[e] = (short)(u >> 16);
              a_l[e] = (short)(u & 0xffffu);
            }
          }
          bf8v b_h = *(const bf8v*)(bh + k);
          bf8v b_l = *(const bf8v*)(bl + k);
          acc = MFMA16(a_h, b_h, acc); acc = MFMA16(a_h, b_l, acc);
          acc = MFMA16(a_l, b_h, acc); acc = MFMA16(a_l, b_l, acc);
        }
#pragma unroll
        for (int r = 0; r < 4; r++) zs3[(kq * 16 + lq * 4 + r) * 17 + lr] = acc[r];
      }
      __syncthreads();
      if (tid < 256) {
        int grow = tid >> 4, gcol = tid & 15;
        float v = 0.f;
#pragma unroll
        for (int q = 0; q < 16; q++) v += zs3[(q * 16 + grow) * 17 + gcol];
        v += b_cp[cgl * 16 + gcol];
        float ahv = tanhf(v);
        unsigned short uh = f2bu(ahv);
        unsigned pkv = ((unsigned)uh << 16) | (unsigned)f2bu(ahv - us2f(uh));
        ast(ahpk + (size_t)(bg * 16 + grow) * 1024 + cgl * 16 + gcol, pkv);
      }
    }
    gridbar2(barsG, lgenG); lgenG++;
    // ---- P4: chunked hi-only logits (gload16 W staging) + exp-sum / top-2 ----
    {
      int base = bid * 125;
      bf16* abuf = (bf16*)(sm + D4_A);
      bf16* wbuf = (bf16*)(sm + D4_W);
      int rg = wv >> 2, cpair = wv & 3;
      f32x4 acc0 = {0.f, 0.f, 0.f, 0.f}, acc1 = {0.f, 0.f, 0.f, 0.f};
      for (int kc = 0; kc < 8; kc++) {
        int k0 = kc * 128;
        __syncthreads();
        {
          int row = tid >> 4, l16 = tid & 15;
          const unsigned* ap = ahpk + (size_t)row * 1024 + k0 + l16 * 8;
          unsigned u0 = ald(ap), u1 = ald(ap + 1), u2 = ald(ap + 2), u3 = ald(ap + 3);
          unsigned u4 = ald(ap + 4), u5 = ald(ap + 5), u6 = ald(ap + 6), u7 = ald(ap + 7);
          uint4 hv;
          hv.x = (u0 >> 16) | (u1 & 0xffff0000u);
          hv.y = (u2 >> 16) | (u3 & 0xffff0000u);
          hv.z = (u4 >> 16) | (u5 & 0xffff0000u);
          hv.w = (u6 >> 16) | (u7 & 0xffff0000u);
          *(uint4*)((char*)abuf + row * 256 + ((l16 * 16) ^ ((row & 7) << 4))) = hv;
        }
#pragma unroll
        for (int r = 0; r < 2; r++) {
          int i = wv * 128 + r * 64 + l;
          int col = i >> 4, j = i & 15;
          int ccol = col < 125 ? col : 124;
          size_t se = (size_t)(base + ccol) * 1024 + k0 + ((size_t)(j ^ (col & 7)) << 3);
          gload16(WoTh + se, (char*)wbuf + wv * 2048 + r * 1024);
        }
        __syncthreads();
#pragma unroll
        for (int s = 0; s < 4; s++) {
          int kl = s * 32 + lq * 8;
          int ar = rg * 16 + lr;
          bf8v a = *(const bf8v*)((char*)abuf + ar * 256 + ((kl * 2) ^ ((ar & 7) << 4)));
          int c0 = cpair * 32 + lr, c1 = c0 + 16;
          bf8v b0 = *(const bf8v*)((char*)wbuf + c0 * 256 + ((kl * 2) ^ ((c0 & 7) << 4)));
          bf8v b1 = *(const bf8v*)((char*)wbuf + c1 * 256 + ((kl * 2) ^ ((c1 & 7) << 4)));
          acc0 = MFMA16(a, b0, acc0);
          acc1 = MFMA16(a, b1, acc1);
        }
      }
      __syncthreads();
      float* e = (float*)(sm + D4_E);
      {
        int cl0 = cpair * 32 + lr;
        if (cl0 < 125) {
#pragma unroll
          for (int r = 0; r < 4; r++)
            e[(rg * 16 + lq * 4 + r) * 129 + cl0] = acc0[r] + b_op[base + cl0];
        }
        int cl1 = cpair * 32 + 16 + lr;
        if (cl1 < 125) {
#pragma unroll
          for (int r = 0; r < 4; r++)
            e[(rg * 16 + lq * 4 + r) * 129 + cl1] = acc1[r] + b_op[base + cl1];
        }
      }
      __syncthreads();
      if (tid < 64) {
        float sm_ = 0.f, v1 = -1e30f, v2 = -1e30f;
        int i1 = 0, i2 = 0;
        for (int c2 = 0; c2 < 125; c2++) {
          float v = e[tid * 129 + c2];
          sm_ += expf(v);
          if (v > v1) { v2 = v1; i2 = i1; v1 = v; i1 = base + c2; }
          else if (v > v2) { v2 = v; i2 = base + c2; }
        }
        astf(rowsum + bid * 64 + tid, sm_);
        astf(rmax + (bid * 64 + tid) * 2 + 0, v1);
        ast((unsigned*)ridx + (bid * 64 + tid) * 2 + 0, (unsigned)i1);
        astf(rmax + (bid * 64 + tid) * 2 + 1, v2);
        ast((unsigned*)ridx + (bid * 64 + tid) * 2 + 1, (unsigned)i2);
      }
    }
    gridbar2(barsG, lgenG); lgenG++;
    // ---- P5: probs write (NT) + candidate refine (f64, NT) + next LSTM ----
    {
      float* psc2 = (float*)(sm + D_PSC2);
      {
        int rr = tid & 63, pp = tid >> 6;
        float s_ = 0.f;
#pragma unroll 4
        for (int cu = pp * 16; cu < pp * 16 + 16; cu++) s_ += aldf(rowsum + cu * 64 + rr);
        psc2[rr * 17 + pp] = s_;
      }
      __syncthreads();
      float* rt = (float*)(sm + D_RT);
      if (tid < 64) {
        float s_ = 0.f;
#pragma unroll
        for (int p2 = 0; p2 < 16; p2++) s_ += psc2[tid * 17 + p2];
        rt[tid] = s_;
      }
      __syncthreads();
      float* e = (float*)(sm + D4_E);
      {
        int base = bid * 125;
        for (int i = tid; i < 8000; i += 1024) {
          int r_ = i / 125, c2 = i - r_ * 125;
          float pv = expf(e[r_ * 129 + c2]) / rt[r_];
          __builtin_nontemporal_store(pv, out + ((size_t)r_ * 32 + st) * 32000 + base + c2);
        }
      }
      if (st < 31) {
        float* gmx = (float*)(sm + D_GMX);
        int* ccnt = (int*)(sm + D_CCN);
        int* cand = (int*)(sm + D_CAND);
        int* y_l = (int*)(sm + D_YL);
        int r16 = tid & 15, ch = tid >> 4;
        int rowg = bg * 16 + r16;
        float vloc[8]; int iloc[8];
        {
          float m_ = -1e30f;
#pragma unroll
          for (int ee = 0; ee < 8; ee++) {
            int ent = ch * 8 + ee;
            vloc[ee] = aldf(rmax + ((size_t)(ent >> 1) * 64 + rowg) * 2 + (ent & 1));
            iloc[ee] = (int)ald((const unsigned*)ridx + ((size_t)(ent >> 1) * 64 + rowg) * 2 + (ent & 1));
            m_ = fmaxf(m_, vloc[ee]);
          }
          gmx[r16 * 65 + ch] = m_;
        }
        if (tid < 16) ccnt[tid] = 0;
        __syncthreads();
        if (tid < 16) {
          float g_ = -1e30f;
#pragma unroll
          for (int j = 0; j < 64; j++) g_ = fmaxf(g_, gmx[tid * 65 + j]);
          gmx[tid * 65 + 64] = g_;
        }
        __syncthreads();
        {
          float thr = gmx[r16 * 65 + 64] - DELTA;
#pragma unroll
          for (int ee = 0; ee < 8; ee++) {
            if (vloc[ee] >= thr) {
              int slot = atomicAdd(&ccnt[r16], 1);
              if (slot < 8) cand[r16 * 8 + slot] = iloc[ee];
            }
          }
        }
        __syncthreads();
        {
          int row2 = wv;
          int rowg2 = bg * 16 + row2;
          int cnt = ccnt[row2]; if (cnt > 8) cnt = 8;
          double bv = -1e30; int bi_ = 0x7fffffff;
          for (int ci = 0; ci < cnt; ci++) {
            int c = cand[row2 * 8 + ci];
            double s_ = 0.0;
            for (int k = l; k < 1024; k += 64) {
              unsigned u = ald(ahpk + (size_t)rowg2 * 1024 + k);
              float av = us2f((unsigned short)(u >> 16)) + us2f((unsigned short)(u & 0xffffu));
              float wv_ = __builtin_nontemporal_load(Wout_f32 + (size_t)k * 32000 + c);
              s_ += (double)av * (double)wv_;
            }
#pragma unroll
            for (int off = 32; off > 0; off >>= 1) s_ += __shfl_down(s_, off);
            if (l == 0) {
              s_ += (double)b_op[c];
              if (s_ > bv || (s_ == bv && c < bi_)) { bv = s_; bi_ = c; }
            }
          }
          if (l == 0) y_l[row2] = bi_;
        }
        __syncthreads();
        dec_lstm7(bg, cgl, tid, sm, hc, hn, dec_emb, KRh, KRl, dec_b, c_);
      }
    }
    bar64(barL, lgenL, lid); lgenL++;
    { unsigned* tp = hc; hc = hn; hn = tp; }
  }
}

// ---------------- host launch ----------------
extern "C" void kernel_launch(void* const* d_in, const int* in_sizes, int n_in,
                              void* d_out, int out_size, void* d_ws, size_t ws_size,
                              hipStream_t stream) {
  (void)in_sizes; (void)n_in; (void)out_size; (void)ws_size;
  const int*   src     = (const int*)  d_in[0];
  const float* enc_emb = (const float*)d_in[1];
  const float* enc_K   = (const float*)d_in[2];
  const float* enc_R   = (const float*)d_in[3];
  const float* enc_b   = (const float*)d_in[4];
  const float* dec_emb = (const float*)d_in[5];
  const float* dec_K   = (const float*)d_in[6];
  const float* dec_R   = (const float*)d_in[7];
  const float* dec_b   = (const float*)d_in[8];
  const float* W_a     = (const float*)d_in[9];
  const float* W_c     = (const float*)d_in[10];
  const float* b_c     = (const float*)d_in[11];
  const float* W_out   = (const float*)d_in[12];
  const float* b_out   = (const float*)d_in[13];
  char* ws = (char*)d_ws;

  hipFuncSetAttribute((const void*)ed_enc_v7, hipFuncAttributeMaxDynamicSharedMemorySize, 163840);
  hipFuncSetAttribute((const void*)ed_dec_v7, hipFuncAttributeMaxDynamicSharedMemorySize, 163840);

  bf16* KpTh = (bf16*)(ws + OKPT_H);
  bf16* KpTl = (bf16*)(ws + OKPT_L);
  bf16* RpTh = (bf16*)(ws + ORPT_H);
  bf16* RpTl = (bf16*)(ws + ORPT_L);
  bf16* xeh  = (bf16*)(ws + OXE_H);
  bf16* xel  = (bf16*)(ws + OXE_L);
  float* hsf = (float*)(ws + OHSF5);
  unsigned* hpkE0 = (unsigned*)(ws + OHPK_E0);
  unsigned* hpkE1 = (unsigned*)(ws + OHPK_E1);
  unsigned* hpkD0 = (unsigned*)(ws + OHPK_D0);
  float* cbuf = (float*)(ws + OCBUF5);
  unsigned* ahpk = (unsigned*)(ws + OAHPK);
  float* rsum = (float*)(ws + ORSUM5);
  float* rmaxp = (float*)(ws + ORMAX5);
  int*  ridxp = (int*)(ws + ORIDX5);
  float* psum = (float*)(ws + OPSUM5);
  unsigned* barsE = (unsigned*)(ws + OBARS5);
  unsigned* barsG = (unsigned*)(ws + OBARS5 + 4096);
  unsigned* barsL = (unsigned*)(ws + OBARS5 + 8192);
  bf16* XkL  = (bf16*)(ws + OXK_L5);
  bf16* XkH  = (bf16*)d_out;
  bf16* WcTh = (bf16*)(ws + OWCT_H);
  bf16* WcTl = (bf16*)(ws + OWCT_L);
  float* pctx = (float*)(ws + OPCTX5);
  float* qbuf = (float*)(ws + OQBUF);
  bf16* WoTh = (bf16*)(ws + OWOT5);
  bf16* KRTh = (bf16*)(ws + OKRTH5);
  bf16* KRTl = (bf16*)(ws + OKRTL5);

  ed_zero_v7<<<512, 256, 0, stream>>>((float4*)(ws + XCH), 131072);
  ed_transpose_split_v7<<<dim3(128, 32), 256, 0, stream>>>(enc_K, KpTh, KpTl, 1024, 4096, 1024, 0, 1);
  ed_transpose_split_v7<<<dim3(128, 32), 256, 0, stream>>>(enc_R, RpTh, RpTl, 1024, 4096, 1024, 0, 1);
  ed_gather_split_v7<<<16384, 256, 0, stream>>>(src, enc_emb, xeh, xel);
  ed_gemm3_v7<<<dim3(32, 128), 256, 0, stream>>>(xeh, xel, KpTh, KpTl, XkH, XkL, 16384, 4096, 1024);
  ed_transpose_split_v7<<<dim3(32, 64), 256, 0, stream>>>(W_c, WcTh, WcTl, 2048, 1024, 2048, 0, 0);
  ed_enc_v7<<<256, 1024, 87040, stream>>>(src, RpTh, RpTl, XkH, XkL, enc_b,
                                          hpkE0, hpkE1, cbuf, hsf, barsE);
  ed_transpose_v7<<<dim3(1000, 32), 256, 0, stream>>>(W_out, WoTh, 1024, 32000, 1024, 0, 0);
  ed_transpose_split_v7<<<dim3(128, 32), 256, 0, stream>>>(dec_K, KRTh, KRTl, 1024, 4096, 2048, 0, 1);
  ed_transpose_split_v7<<<dim3(128, 32), 256, 0, stream>>>(dec_R, KRTh, KRTl, 1024, 4096, 2048, 1024, 1);
  ed_dec_v7<<<256, 1024, 150528, stream>>>(src, KRTh, KRTl, dec_b, WcTh, WcTl, b_c,
                                           WoTh, b_out, W_out, dec_emb, W_a, qbuf, hsf,
                                           hpkE0, hpkD0, cbuf, pctx, psum, ahpk,
                                           rsum, rmaxp, ridxp, (float*)d_out, barsG, barsL);
}

// Round 8
// 12432.891 us; speedup vs baseline: 1.1607x; 1.1607x over previous
//
#include <hip/hip_runtime.h>
#include <hip/hip_bf16.h>

typedef __hip_bfloat16 bf16;
typedef short bf8v __attribute__((ext_vector_type(8)));   // 8 x bf16 (4 VGPR)
typedef float f32x4 __attribute__((ext_vector_type(4)));

#define DEVINL __device__ __forceinline__
#define MFMA16(a, b, c) __builtin_amdgcn_mfma_f32_16x16x32_bf16((a), (b), (c), 0, 0, 0)

DEVINL float us2f(unsigned short u) { unsigned v = ((unsigned)u) << 16; return __uint_as_float(v); }
DEVINL float b2f(bf16 x) { return __bfloat162float(x); }
DEVINL bf16 f2b(float x) { return __float2bfloat16(x); }
DEVINL float sigf(float x) { return 1.0f / (1.0f + expf(-x)); }
DEVINL unsigned short f2bu(float f) { bf16 h = __float2bfloat16(f); return *(unsigned short*)&h; }

DEVINL void gload16(const void* g, void* l) {
  __builtin_amdgcn_global_load_lds((const __attribute__((address_space(1))) void*)g,
                                   (__attribute__((address_space(3))) void*)l, 16, 0, 0);
}

// ---- relaxed agent-scope atomics ----
DEVINL unsigned ald(const unsigned* p) {
  return __hip_atomic_load(p, __ATOMIC_RELAXED, __HIP_MEMORY_SCOPE_AGENT);
}
DEVINL void ast(unsigned* p, unsigned v) {
  __hip_atomic_store(p, v, __ATOMIC_RELAXED, __HIP_MEMORY_SCOPE_AGENT);
}
DEVINL float aldf(const float* p) { unsigned u = ald((const unsigned*)p); return __uint_as_float(u); }
DEVINL void astf(float* p, float v) { ast((unsigned*)p, __float_as_uint(v)); }

// ---- global 256-block barrier (8 groups x 32), parity-buffered ----
DEVINL void gridbar2(unsigned* bars, unsigned lgen) {
  __syncthreads();
  if (threadIdx.x == 0) {
    unsigned s = lgen & 1;
    unsigned g = blockIdx.x >> 5;
    unsigned* grp = bars + (g * 2 + s) * 16;
    unsigned* top = bars + (16 + s) * 16;
    unsigned* gen = bars + 288;
    unsigned t = __hip_atomic_fetch_add(grp, 1u, __ATOMIC_RELAXED, __HIP_MEMORY_SCOPE_AGENT);
    if (t == 31u) {
      ast(grp, 0u);
      unsigned tt = __hip_atomic_fetch_add(top, 1u, __ATOMIC_RELAXED, __HIP_MEMORY_SCOPE_AGENT);
      if (tt == 7u) {
        ast(top, 0u);
        asm volatile("s_waitcnt vmcnt(0)");
        ast(gen, lgen + 1u);
      }
    }
    while (ald(gen) <= lgen) __builtin_amdgcn_s_sleep(4);
  }
  __syncthreads();
}

// ---- local 64-block barrier (2 groups x 32) ----
DEVINL void bar64(unsigned* b, unsigned lgen, int lid) {
  __syncthreads();
  if (threadIdx.x == 0) {
    unsigned s = lgen & 1;
    unsigned* grp = b + (((unsigned)(lid >> 5) & 1u) * 2 + s) * 16;
    unsigned* top = b + (4 + s) * 16;
    unsigned* gen = b + 96;
    unsigned t = __hip_atomic_fetch_add(grp, 1u, __ATOMIC_RELAXED, __HIP_MEMORY_SCOPE_AGENT);
    if (t == 31u) {
      ast(grp, 0u);
      unsigned tt = __hip_atomic_fetch_add(top, 1u, __ATOMIC_RELAXED, __HIP_MEMORY_SCOPE_AGENT);
      if (tt == 1u) {
        ast(top, 0u);
        asm volatile("s_waitcnt vmcnt(0)");
        ast(gen, lgen + 1u);
      }
    }
    while (ald(gen) <= lgen) __builtin_amdgcn_s_sleep(2);
  }
  __syncthreads();
}

// ---------------- ws layout (bytes); total <= 272,629,760 ----
#define OKPT_H  ((size_t)0)
#define OKPT_L  ((size_t)8388608)
#define ORPT_H  ((size_t)16777216)
#define ORPT_L  ((size_t)25165824)
#define OXE_H   ((size_t)35651584)
#define OXE_L   ((size_t)69206016)
#define OHSF5   ((size_t)35651584)
#define XCH     ((size_t)136314880)
#define OHPK_E0 (XCH + 0)
#define OHPK_E1 (XCH + 262144)
#define OHPK_D0 (XCH + 524288)
#define OCBUF5  (XCH + 1048576)
#define OAHPK   (XCH + 1310720)
#define ORSUM5  (XCH + 1572864)
#define ORMAX5  (XCH + 1638400)
#define ORIDX5  (XCH + 1769472)
#define OPSUM5  (XCH + 1900544)
#define OBARS5  (XCH + 1901568)
#define OYBUF   (XCH + 1917952)
#define OXK_L5  ((size_t)138412032)
#define OWCT_H  ((size_t)0)
#define OWCT_L  ((size_t)4194304)
#define OPCTX5  ((size_t)8388608)
#define OQBUF   ORPT_H              /* 256 KB over dead RpT */
#define OWAB    (ORPT_H + 262144)   /* 2 MB bf16 W_a over dead RpT */
#define OWOT5   ((size_t)138412032)
#define OKRTH5  ((size_t)203948032)
#define OKRTL5  ((size_t)220725248)

#define DELTA   1e-4f

// decoder LDS pool offsets (pool 150528)
#define D_LH   0
#define D_LL   32768
#define D_ZS   65536
#define D_KBH  83968
#define D_KBL  116736
#define D4_A   0
#define D4_W   16384
#define D4_E   49152
#define D_WA   0
#define D_ES   65536
#define D_ZS3  0
#define D_PSC2 0
#define D_RV   0
#define D_RR   2048
#define D_CCN  4096
#define D_CAND 4160
#define D_RS   4224
#define D_RC   4352
#define D_YL   149504
#define D_INV  149568
#define D_RT   149632

// ---------------- utility kernels ----------------
__global__ void ed_zero_v8(float4* p, int n) {
  int i = blockIdx.x * 256 + threadIdx.x;
  if (i < n) p[i] = make_float4(0.f, 0.f, 0.f, 0.f);
}

__global__ void ed_cvt_v8(const float* __restrict__ in, bf16* __restrict__ out, int n) {
  int i = (blockIdx.x * 256 + threadIdx.x) * 4;
  if (i + 3 < n) {
    float4 v = *(const float4*)(in + i);
    ushort4 o;
    o.x = f2bu(v.x); o.y = f2bu(v.y); o.z = f2bu(v.z); o.w = f2bu(v.w);
    *(ushort4*)(out + i) = o;
  }
}

__global__ void ed_transpose_v8(const float* __restrict__ in, bf16* __restrict__ out,
                                int R, int C, int ostride, int ooff, int perm) {
  __shared__ float tile[32][33];
  int c0 = blockIdx.x * 32, r0 = blockIdx.y * 32;
  int tx = threadIdx.x & 31, ty0 = threadIdx.x >> 5;
#pragma unroll
  for (int i = 0; i < 4; i++) {
    int ty = ty0 + i * 8;
    tile[ty][tx] = in[(size_t)(r0 + ty) * C + c0 + tx];
  }
  __syncthreads();
#pragma unroll
  for (int i = 0; i < 4; i++) {
    int ty = ty0 + i * 8;
    int c = c0 + ty;
    int oc = perm ? ((c & 1023) * 4 + (c >> 10)) : c;
    out[(size_t)oc * ostride + ooff + r0 + tx] = f2b(tile[tx][ty]);
  }
}

__global__ void ed_transpose_split_v8(const float* __restrict__ in, bf16* __restrict__ oh,
                                      bf16* __restrict__ ol, int R, int C, int ostride,
                                      int ooff, int perm) {
  __shared__ float tile[32][33];
  int c0 = blockIdx.x * 32, r0 = blockIdx.y * 32;
  int tx = threadIdx.x & 31, ty0 = threadIdx.x >> 5;
#pragma unroll
  for (int i = 0; i < 4; i++) {
    int ty = ty0 + i * 8;
    tile[ty][tx] = in[(size_t)(r0 + ty) * C + c0 + tx];
  }
  __syncthreads();
#pragma unroll
  for (int i = 0; i < 4; i++) {
    int ty = ty0 + i * 8;
    int c = c0 + ty;
    int oc = perm ? ((c & 1023) * 4 + (c >> 10)) : c;
    float v = tile[tx][ty];
    bf16 hh = f2b(v);
    size_t o = (size_t)oc * ostride + ooff + r0 + tx;
    oh[o] = hh;
    ol[o] = f2b(v - b2f(hh));
  }
}

__global__ void ed_gather_split_v8(const int* __restrict__ src, const float* __restrict__ emb,
                                   bf16* __restrict__ xh, bf16* __restrict__ xl) {
  int bid = blockIdx.x;
  int t = bid >> 6, b = bid & 63;
  int tok = src[b * 256 + t];
  const float* rowp = emb + (size_t)tok * 1024;
  int i = threadIdx.x * 4;
  float4 v = *(const float4*)(rowp + i);
  bf16 h0 = f2b(v.x), h1 = f2b(v.y), h2 = f2b(v.z), h3 = f2b(v.w);
  ushort4 oh, ol;
  oh.x = *(unsigned short*)&h0; oh.y = *(unsigned short*)&h1;
  oh.z = *(unsigned short*)&h2; oh.w = *(unsigned short*)&h3;
  ol.x = f2bu(v.x - b2f(h0)); ol.y = f2bu(v.y - b2f(h1));
  ol.z = f2bu(v.z - b2f(h2)); ol.w = f2bu(v.w - b2f(h3));
  *(ushort4*)(xh + (size_t)bid * 1024 + i) = oh;
  *(ushort4*)(xl + (size_t)bid * 1024 + i) = ol;
}

// ---------------- split-precision GEMM (3-term), split output (Xk) ----------------
__global__ __launch_bounds__(256, 2) void ed_gemm3_v8(
    const bf16* __restrict__ Ah, const bf16* __restrict__ Al,
    const bf16* __restrict__ Bh, const bf16* __restrict__ Bl,
    bf16* __restrict__ Ch, bf16* __restrict__ Cl, int M, int N, int K) {
  __shared__ __align__(16) bf16 Ash[128 * 32];
  __shared__ __align__(16) bf16 Asl[128 * 32];
  __shared__ __align__(16) bf16 Bsh[128 * 32];
  __shared__ __align__(16) bf16 Bsl[128 * 32];
  int m0 = blockIdx.y * 128, n0 = blockIdx.x * 128;
  int tid = threadIdx.x, w = tid >> 6, l = tid & 63;
  int wm = w >> 1, wn = w & 1;
  int lr = l & 15, lq = l >> 4;
  f32x4 acc[4][4] = {};
  for (int k0 = 0; k0 < K; k0 += 32) {
    __syncthreads();
#pragma unroll
    for (int j = 0; j < 2; j++) {
      int o = (w * 2 + j) * 1024 + l * 16;
      int rrow = o >> 6, kk = (o & 63) >> 1;
      gload16(Ah + (size_t)(m0 + rrow) * K + k0 + kk, (char*)Ash + (w * 2 + j) * 1024);
      gload16(Al + (size_t)(m0 + rrow) * K + k0 + kk, (char*)Asl + (w * 2 + j) * 1024);
      gload16(Bh + (size_t)(n0 + rrow) * K + k0 + kk, (char*)Bsh + (w * 2 + j) * 1024);
      gload16(Bl + (size_t)(n0 + rrow) * K + k0 + kk, (char*)Bsl + (w * 2 + j) * 1024);
    }
    __syncthreads();
#pragma unroll
    for (int mi = 0; mi < 4; mi++) {
      bf8v a_h = *(const bf8v*)(Ash + (wm * 64 + mi * 16 + lr) * 32 + lq * 8);
      bf8v a_l = *(const bf8v*)(Asl + (wm * 64 + mi * 16 + lr) * 32 + lq * 8);
#pragma unroll
      for (int ni = 0; ni < 4; ni++) {
        bf8v b_h = *(const bf8v*)(Bsh + (wn * 64 + ni * 16 + lr) * 32 + lq * 8);
        bf8v b_l = *(const bf8v*)(Bsl + (wn * 64 + ni * 16 + lr) * 32 + lq * 8);
        acc[mi][ni] = MFMA16(a_h, b_h, acc[mi][ni]);
        acc[mi][ni] = MFMA16(a_h, b_l, acc[mi][ni]);
        acc[mi][ni] = MFMA16(a_l, b_h, acc[mi][ni]);
      }
    }
  }
#pragma unroll
  for (int mi = 0; mi < 4; mi++)
#pragma unroll
    for (int ni = 0; ni < 4; ni++)
#pragma unroll
      for (int r = 0; r < 4; r++) {
        float v = acc[mi][ni][r];
        bf16 hh = f2b(v);
        size_t idx = (size_t)(m0 + wm * 64 + mi * 16 + lq * 4 + r) * N + n0 + wn * 64 + ni * 16 + lr;
        Ch[idx] = hh;
        Cl[idx] = f2b(v - b2f(hh));
      }
}

// ---------------- encoder: per-bg local barriers; hsf cached ----------------
__global__ __launch_bounds__(1024, 4) void ed_enc_v8(
    const int* __restrict__ src, const bf16* __restrict__ Rh, const bf16* __restrict__ Rl,
    const bf16* __restrict__ Xh, const bf16* __restrict__ Xl, const float* __restrict__ enc_b,
    unsigned* hpk0, unsigned* hpk1, float* __restrict__ cbuf,
    float* __restrict__ hsf, unsigned* barsE) {
  extern __shared__ char sm[];
  bf16* lh = (bf16*)sm;
  bf16* ll = (bf16*)(sm + 32768);
  float* zs = (float*)(sm + 65536);
  float* xkf = (float*)(sm + 82944);
  int bid = blockIdx.x, tid = threadIdx.x;
  int bg = bid >> 6, cg = bid & 63, lid = bid & 63;
  unsigned* barL = barsE + bg * 128;
  int wv = tid >> 6, l = tid & 63, lr = l & 15, lq = l >> 4;
  int kq = wv >> 2, cs = wv & 3;
  int srow = tid >> 6, sj0 = (tid & 63) * 16;
  int grow = tid >> 4, gul = tid & 15;
  bf8v Rh_[8], Rl_[8];
  {
    const bf16* bh = Rh + (size_t)(cg * 64 + cs * 16 + lr) * 1024 + kq * 256 + lq * 8;
    const bf16* bl = Rl + (size_t)(cg * 64 + cs * 16 + lr) * 1024 + kq * 256 + lq * 8;
#pragma unroll
    for (int i = 0; i < 8; i++) {
      Rh_[i] = *(const bf8v*)(bh + i * 32);
      Rl_[i] = *(const bf8v*)(bl + i * 32);
    }
  }
  float bi[4];
  float c_ = 0.f;
  if (tid < 256) {
#pragma unroll
    for (int g = 0; g < 4; g++) {
      int colp = cg * 64 + gul * 4 + g;
      bi[g] = enc_b[(colp & 3) * 1024 + (colp >> 2)];
    }
  }
  unsigned *hc = hpk0, *hn = hpk1;
  unsigned lgen = 0;
  for (int t = 0; t < 256; t++) {
    {
      const unsigned* hrow = hc + (size_t)(bg * 16 + srow) * 1024 + sj0;
      unsigned u[16];
#pragma unroll
      for (int j = 0; j < 16; j++) u[j] = ald(hrow + j);
      int r8 = (srow & 7) << 3;
#pragma unroll
      for (int j = 0; j < 16; j += 2) {
        int es = (sj0 + j) ^ r8;
        *(unsigned*)((char*)lh + srow * 2048 + es * 2) = (u[j] >> 16) | (u[j + 1] & 0xffff0000u);
        *(unsigned*)((char*)ll + srow * 2048 + es * 2) = (u[j] & 0xffffu) | (u[j + 1] << 16);
      }
    }
    {
      int xr = tid >> 6, xc = tid & 63;
      size_t xi = ((size_t)t * 64 + bg * 16 + xr) * 4096 + cg * 64 + xc;
      unsigned short xh = __builtin_nontemporal_load((const unsigned short*)(Xh + xi));
      unsigned short xl = __builtin_nontemporal_load((const unsigned short*)(Xl + xi));
      xkf[xr * 64 + xc] = us2f(xh) + us2f(xl);
    }
    __syncthreads();
    {
      f32x4 acc = {0.f, 0.f, 0.f, 0.f};
      int r8 = (lr & 7) << 3;
#pragma unroll
      for (int i = 0; i < 8; i++) {
        int e0 = kq * 256 + i * 32 + lq * 8;
        int es = e0 ^ r8;
        bf8v a_h = *(const bf8v*)((char*)lh + lr * 2048 + es * 2);
        bf8v a_l = *(const bf8v*)((char*)ll + lr * 2048 + es * 2);
        acc = MFMA16(a_h, Rh_[i], acc);
        acc = MFMA16(a_h, Rl_[i], acc);
        acc = MFMA16(a_l, Rh_[i], acc);
        acc = MFMA16(a_l, Rl_[i], acc);
      }
#pragma unroll
      for (int r = 0; r < 4; r++) zs[(kq * 16 + lq * 4 + r) * 68 + cs * 16 + lr] = acc[r];
    }
    __syncthreads();
    if (tid < 256) {
      int b_ = bg * 16 + grow, u = cg * 16 + gul;
      float zz[4];
#pragma unroll
      for (int g = 0; g < 4; g++) {
        int cc = gul * 4 + g;
        zz[g] = zs[(0 + grow) * 68 + cc] + zs[(16 + grow) * 68 + cc] +
                zs[(32 + grow) * 68 + cc] + zs[(48 + grow) * 68 + cc] +
                xkf[grow * 64 + cc] + bi[g];
      }
      float iv = sigf(zz[0]), fv = sigf(zz[1]), gv = tanhf(zz[2]), ov = sigf(zz[3]);
      float cn = fv * c_ + iv * gv;
      float hnv = ov * tanhf(cn);
      bool m = src[b_ * 256 + t] > 0;
      int es = u ^ ((grow & 7) << 3);
      float hold = b2f(*(const bf16*)((char*)lh + grow * 2048 + es * 2)) +
                   b2f(*(const bf16*)((char*)ll + grow * 2048 + es * 2));
      float hv = m ? hnv : hold;
      c_ = m ? cn : c_;
      unsigned short uh = f2bu(hv);
      unsigned pkv = ((unsigned)uh << 16) | (unsigned)f2bu(hv - us2f(uh));
      ast(hn + (size_t)b_ * 1024 + u, pkv);
      hsf[((size_t)t * 64 + b_) * 1024 + u] = hv;
    }
    bar64(barL, lgen, lid);
    lgen++;
    unsigned* tp = hc; hc = hn; hn = tp;
  }
  if (tid < 256) cbuf[(size_t)(bg * 16 + grow) * 1024 + cg * 16 + gul] = c_;
}

// ---------------- decoder LSTM (chunked KRT staging via gload16) ----------------
DEVINL void dec_lstm8(int bg, int cgl, int tid, char* sm,
                      const unsigned* hc, unsigned* hn,
                      const float* __restrict__ dec_emb,
                      const bf16* __restrict__ Kh, const bf16* __restrict__ Kl,
                      const float* __restrict__ dec_b, float& c_) {
  bf16* lh = (bf16*)(sm + D_LH);
  bf16* ll = (bf16*)(sm + D_LL);
  {
    int srow = tid >> 6, sl = tid & 63;
    const unsigned* hrow = hc + (size_t)(bg * 16 + srow) * 1024 + sl * 16;
    unsigned u[16];
#pragma unroll
    for (int j = 0; j < 16; j++) u[j] = ald(hrow + j);
    uint4 ha, hb, la, lb;
    ha.x = (u[0] >> 16) | (u[1] & 0xffff0000u);  ha.y = (u[2] >> 16) | (u[3] & 0xffff0000u);
    ha.z = (u[4] >> 16) | (u[5] & 0xffff0000u);  ha.w = (u[6] >> 16) | (u[7] & 0xffff0000u);
    hb.x = (u[8] >> 16) | (u[9] & 0xffff0000u);  hb.y = (u[10] >> 16) | (u[11] & 0xffff0000u);
    hb.z = (u[12] >> 16) | (u[13] & 0xffff0000u); hb.w = (u[14] >> 16) | (u[15] & 0xffff0000u);
    la.x = (u[0] & 0xffffu) | (u[1] << 16);  la.y = (u[2] & 0xffffu) | (u[3] << 16);
    la.z = (u[4] & 0xffffu) | (u[5] << 16);  la.w = (u[6] & 0xffffu) | (u[7] << 16);
    lb.x = (u[8] & 0xffffu) | (u[9] << 16);  lb.y = (u[10] & 0xffffu) | (u[11] << 16);
    lb.z = (u[12] & 0xffffu) | (u[13] << 16); lb.w = (u[14] & 0xffffu) | (u[15] << 16);
    int swz = (srow & 7) << 4;
    char* rbh = (char*)lh + srow * 2048;
    char* rbl = (char*)ll + srow * 2048;
    *(uint4*)(rbh + ((sl * 32) ^ swz)) = ha;
    *(uint4*)(rbh + ((sl * 32 + 16) ^ swz)) = hb;
    *(uint4*)(rbl + ((sl * 32) ^ swz)) = la;
    *(uint4*)(rbl + ((sl * 32 + 16) ^ swz)) = lb;
  }
  int wv = tid >> 6, l = tid & 63, lr = l & 15, lq = l >> 4;
  int kg2 = wv >> 2, cs = wv & 3;
  bf16* kbh = (bf16*)(sm + D_KBH);
  bf16* kbl = (bf16*)(sm + D_KBL);
  const int* y_l = (const int*)(sm + D_YL);
  float* zs = (float*)(sm + D_ZS);
  f32x4 acc = {0.f, 0.f, 0.f, 0.f};
  int colB = cs * 16 + lr;
  int bswz = (colB & 7) << 4;
  int aswz = (lr & 7) << 4;
  for (int c = 0; c < 8; c++) {
    __syncthreads();
#pragma unroll
    for (int r = 0; r < 2; r++) {
      int i = wv * 128 + r * 64 + l;
      int col = i >> 5, j = i & 31;
      size_t se = (size_t)(cgl * 64 + col) * 2048 + c * 256 + ((size_t)(j ^ (col & 7)) << 3);
      gload16(Kh + se, (char*)kbh + wv * 2048 + r * 1024);
      gload16(Kl + se, (char*)kbl + wv * 2048 + r * 1024);
    }
    __syncthreads();
#pragma unroll
    for (int s = 0; s < 2; s++) {
      int kl = kg2 * 64 + s * 32 + lq * 8;
      bf8v b_h = *(const bf8v*)((char*)kbh + colB * 512 + ((kl * 2) ^ bswz));
      bf8v b_l = *(const bf8v*)((char*)kbl + colB * 512 + ((kl * 2) ^ bswz));
      int gk = c * 256 + kl;
      bf8v a_h, a_l;
      if (gk < 1024) {
        const float* xr = dec_emb + (size_t)y_l[lr] * 1024 + gk;
        float4 v0 = *(const float4*)xr;
        float4 v1 = *(const float4*)(xr + 4);
        float vs[8] = {v0.x, v0.y, v0.z, v0.w, v1.x, v1.y, v1.z, v1.w};
#pragma unroll
        for (int e = 0; e < 8; e++) {
          unsigned short uh = f2bu(vs[e]);
          a_h[e] = (short)uh;
          a_l[e] = (short)f2bu(vs[e] - us2f(uh));
        }
      } else {
        int hk = gk - 1024;
        a_h = *(const bf8v*)((char*)lh + lr * 2048 + ((hk * 2) ^ aswz));
        a_l = *(const bf8v*)((char*)ll + lr * 2048 + ((hk * 2) ^ aswz));
      }
      acc = MFMA16(a_h, b_h, acc);
      acc = MFMA16(a_h, b_l, acc);
      acc = MFMA16(a_l, b_h, acc);
      acc = MFMA16(a_l, b_l, acc);
    }
  }
#pragma unroll
  for (int r = 0; r < 4; r++) zs[(kg2 * 16 + lq * 4 + r) * 68 + cs * 16 + lr] = acc[r];
  __syncthreads();
  if (tid < 256) {
    int grow = tid >> 4, gul = tid & 15;
    int b_ = bg * 16 + grow;
    float zz[4];
#pragma unroll
    for (int g = 0; g < 4; g++) {
      int cc = gul * 4 + g;
      int colp = cgl * 64 + cc;
      float v = zs[(0 + grow) * 68 + cc] + zs[(16 + grow) * 68 + cc] +
                zs[(32 + grow) * 68 + cc] + zs[(48 + grow) * 68 + cc];
      zz[g] = v + dec_b[(colp & 3) * 1024 + (colp >> 2)];
    }
    float iv = sigf(zz[0]), fv = sigf(zz[1]), gv = tanhf(zz[2]), ov = sigf(zz[3]);
    float cn = fv * c_ + iv * gv;
    c_ = cn;
    float hv = ov * tanhf(cn);
    unsigned short uh = f2bu(hv);
    unsigned pkv = ((unsigned)uh << 16) | (unsigned)f2bu(hv - us2f(uh));
    ast(hn + (size_t)b_ * 1024 + cgl * 16 + gul, pkv);
  }
}

// ---------------- decoder persistent kernel ----------------
__global__ __launch_bounds__(1024, 4) void ed_dec_v8(
    const int* __restrict__ src,
    const bf16* __restrict__ KRh, const bf16* __restrict__ KRl, const float* __restrict__ dec_b,
    const bf16* __restrict__ WcTh, const bf16* __restrict__ WcTl, const float* __restrict__ b_cp,
    const bf16* __restrict__ WoTh, const float* __restrict__ b_op,
    const float* __restrict__ Wout_f32, const float* __restrict__ dec_emb,
    const bf16* __restrict__ WaB, float* __restrict__ qbuf,
    const float* __restrict__ hsf,
    unsigned* hpkA, unsigned* hpkB, float* __restrict__ cbuf,
    float* __restrict__ pctx, float* __restrict__ psum, unsigned* ahpk,
    float* __restrict__ rowsum, float* __restrict__ rmax, int* __restrict__ ridx,
    unsigned* ybuf, float* __restrict__ out, unsigned* barsG, unsigned* barsL) {
  extern __shared__ char sm[];
  int bid = blockIdx.x, tid = threadIdx.x;
  int bg = bid >> 6, cgl = bid & 63, lid = bid & 63;
  unsigned* barL = barsL + bg * 128;
  int wv = tid >> 6, l = tid & 63, lr = l & 15, lq = l >> 4;
  float c_ = 0.f;
  if (tid < 256) c_ = cbuf[(size_t)(bg * 16 + (tid >> 4)) * 1024 + cgl * 16 + (tid & 15)];
  unsigned *hc = hpkA, *hn = hpkB;
  unsigned lgenL = 0, lgenG = 0;

  if (tid < 16) ((int*)(sm + D_YL))[tid] = 1;
  __syncthreads();
  dec_lstm8(bg, cgl, tid, sm, hc, hn, dec_emb, KRh, KRl, dec_b, c_);
  bar64(barL, lgenL, lid); lgenL++;
  { unsigned* tp = hc; hc = hn; hn = tp; }

  for (int st = 0; st < 32; st++) {
    // ---- PQ: q[b] = W_a @ h[b] (bf16 W_a); active blocks cgl<16 ----
    if (cgl < 16) {
      int colb = cgl * 64;
      int kq = wv >> 2, nq = wv & 3;
      float* zs = (float*)(sm + D_ZS);
      f32x4 acc = {0.f, 0.f, 0.f, 0.f};
      const unsigned* hrow = hc + (size_t)(bg * 16 + lr) * 1024;
      const bf16* warow = WaB + (size_t)(colb + nq * 16 + lr) * 1024;
#pragma unroll
      for (int i = 0; i < 8; i++) {
        int k = kq * 256 + i * 32 + lq * 8;
        bf8v a;
        const unsigned* hp = hrow + k;
#pragma unroll
        for (int e = 0; e < 8; e++) a[e] = (short)(ald(hp + e) >> 16);
        bf8v b = *(const bf8v*)(warow + k);
        acc = MFMA16(a, b, acc);
      }
#pragma unroll
      for (int r = 0; r < 4; r++) zs[(kq * 16 + lq * 4 + r) * 68 + nq * 16 + lr] = acc[r];
      __syncthreads();
      {
        int mrow = tid >> 6, col = tid & 63;
        float v = zs[(0 + mrow) * 68 + col] + zs[(16 + mrow) * 68 + col] +
                  zs[(32 + mrow) * 68 + col] + zs[(48 + mrow) * 68 + col];
        astf(qbuf + (size_t)(bg * 16 + mrow) * 1024 + colb + col, v);
      }
    }
    bar64(barL, lgenL, lid); lgenL++;
    // ---- P1: fused scores+ctx, single pass over hsf; block = (b, kg) ----
    {
      int b_ = bid >> 2, kg = bid & 3;
      float* wacc = (float*)(sm + D_WA);   // [16][1024], stored [w][j*64+l]
      float* es = (float*)(sm + D_ES);     // [16]
      float qr[16];
      {
        const float* qb = qbuf + (size_t)b_ * 1024 + l * 16;
        *(float4*)&qr[0]  = *(const float4*)(qb);
        *(float4*)&qr[4]  = *(const float4*)(qb + 4);
        *(float4*)&qr[8]  = *(const float4*)(qb + 8);
        *(float4*)&qr[12] = *(const float4*)(qb + 12);
      }
      float a16[16];
#pragma unroll
      for (int j = 0; j < 16; j++) a16[j] = 0.f;
      float esum = 0.f;
#pragma unroll
      for (int i = 0; i < 4; i++) {
        int kglob = kg * 64 + wv * 4 + i;
        const float* hrow = hsf + ((size_t)kglob * 64 + b_) * 1024 + l * 16;
        float4 v0 = *(const float4*)hrow;
        float4 v1 = *(const float4*)(hrow + 4);
        float4 v2 = *(const float4*)(hrow + 8);
        float4 v3 = *(const float4*)(hrow + 12);
        float vv[16] = {v0.x, v0.y, v0.z, v0.w, v1.x, v1.y, v1.z, v1.w,
                        v2.x, v2.y, v2.z, v2.w, v3.x, v3.y, v3.z, v3.w};
        float p = 0.f;
#pragma unroll
        for (int j = 0; j < 16; j++) p += qr[j] * vv[j];
#pragma unroll
        for (int off = 32; off > 0; off >>= 1) p += __shfl_xor(p, off);
        float e = (src[b_ * 256 + kglob] > 0) ? expf(p) : 0.f;
        esum += e;
#pragma unroll
        for (int j = 0; j < 16; j++) a16[j] += e * vv[j];
      }
#pragma unroll
      for (int j = 0; j < 16; j++) wacc[wv * 1024 + j * 64 + l] = a16[j];
      if (l == 0) es[wv] = esum;
      __syncthreads();
      {
        float v = 0.f;
#pragma unroll
        for (int w2 = 0; w2 < 16; w2++) v += wacc[w2 * 1024 + tid];
        int logical = (tid & 63) * 16 + (tid >> 6);
        astf(pctx + ((size_t)kg * 64 + b_) * 1024 + logical, v);
      }
      if (tid == 0) {
        float s_ = 0.f;
#pragma unroll
        for (int w2 = 0; w2 < 16; w2++) s_ += es[w2];
        astf(psum + kg * 64 + b_, s_);
      }
    }
    bar64(barL, lgenL, lid); lgenL++;
    // ---- P3: ctx-reduce + ah = tanh([ctx,h]@W_c + b_c); block = (bg, 16-col) ----
    {
      float* inv_l = (float*)(sm + D_INV);
      if (tid < 16) {
        int rb = bg * 16 + tid;
        float sg = aldf(psum + rb) + aldf(psum + 64 + rb) +
                   aldf(psum + 128 + rb) + aldf(psum + 192 + rb);
        inv_l[tid] = 1.0f / sg;
      }
      __syncthreads();
      float* zs3 = (float*)(sm + D_ZS3);
      {
        int kq = wv;
        f32x4 acc = {0.f, 0.f, 0.f, 0.f};
        const bf16* bh = WcTh + (size_t)(cgl * 16 + lr) * 2048;
        const bf16* bl = WcTl + (size_t)(cgl * 16 + lr) * 2048;
        float inv = inv_l[lr];
#pragma unroll
        for (int i = 0; i < 4; i++) {
          int k = kq * 128 + i * 32 + lq * 8;
          bf8v a_h, a_l;
          if (k < 1024) {
            const float* p0 = pctx + (size_t)(bg * 16 + lr) * 1024 + k;
#pragma unroll
            for (int e = 0; e < 8; e++) {
              float v = (aldf(p0 + e) + aldf(p0 + 65536 + e) +
                         aldf(p0 + 131072 + e) + aldf(p0 + 196608 + e)) * inv;
              unsigned short uh = f2bu(v);
              a_h[e] = (short)uh;
              a_l[e] = (short)f2bu(v - us2f(uh));
            }
          } else {
            const unsigned* hp = hc + (size_t)(bg * 16 + lr) * 1024 + (k - 1024);
#pragma unroll
            for (int e = 0; e < 8; e++) {
              unsigned u = ald(hp + e);
              a_h[e] = (short)(u >> 16);
              a_l[e] = (short)(u & 0xffffu);
            }
          }
          bf8v b_h = *(const bf8v*)(bh + k);
          bf8v b_l = *(const bf8v*)(bl + k);
          acc = MFMA16(a_h, b_h, acc); acc = MFMA16(a_h, b_l, acc);
          acc = MFMA16(a_l, b_h, acc); acc = MFMA16(a_l, b_l, acc);
        }
#pragma unroll
        for (int r = 0; r < 4; r++) zs3[(kq * 16 + lq * 4 + r) * 17 + lr] = acc[r];
      }
      __syncthreads();
      if (tid < 256) {
        int grow = tid >> 4, gcol = tid & 15;
        float v = 0.f;
#pragma unroll
        for (int q = 0; q < 16; q++) v += zs3[(q * 16 + grow) * 17 + gcol];
        v += b_cp[cgl * 16 + gcol];
        float ahv = tanhf(v);
        unsigned short uh = f2bu(ahv);
        unsigned pkv = ((unsigned)uh << 16) | (unsigned)f2bu(ahv - us2f(uh));
        ast(ahpk + (size_t)(bg * 16 + grow) * 1024 + cgl * 16 + gcol, pkv);
      }
    }
    gridbar2(barsG, lgenG); lgenG++;
    // ---- P4: chunked hi-only logits (gload16 W staging) + exp-sum / top-2 ----
    {
      int base = bid * 125;
      bf16* abuf = (bf16*)(sm + D4_A);
      bf16* wbuf = (bf16*)(sm + D4_W);
      int rg = wv >> 2, cpair = wv & 3;
      f32x4 acc0 = {0.f, 0.f, 0.f, 0.f}, acc1 = {0.f, 0.f, 0.f, 0.f};
      for (int kc = 0; kc < 8; kc++) {
        int k0 = kc * 128;
        __syncthreads();
        {
          int row = tid >> 4, l16 = tid & 15;
          const unsigned* ap = ahpk + (size_t)row * 1024 + k0 + l16 * 8;
          unsigned u0 = ald(ap), u1 = ald(ap + 1), u2 = ald(ap + 2), u3 = ald(ap + 3);
          unsigned u4 = ald(ap + 4), u5 = ald(ap + 5), u6 = ald(ap + 6), u7 = ald(ap + 7);
          uint4 hv;
          hv.x = (u0 >> 16) | (u1 & 0xffff0000u);
          hv.y = (u2 >> 16) | (u3 & 0xffff0000u);
          hv.z = (u4 >> 16) | (u5 & 0xffff0000u);
          hv.w = (u6 >> 16) | (u7 & 0xffff0000u);
          *(uint4*)((char*)abuf + row * 256 + ((l16 * 16) ^ ((row & 7) << 4))) = hv;
        }
#pragma unroll
        for (int r = 0; r < 2; r++) {
          int i = wv * 128 + r * 64 + l;
          int col = i >> 4, j = i & 15;
          int ccol = col < 125 ? col : 124;
          size_t se = (size_t)(base + ccol) * 1024 + k0 + ((size_t)(j ^ (col & 7)) << 3);
          gload16(WoTh + se, (char*)wbuf + wv * 2048 + r * 1024);
        }
        __syncthreads();
#pragma unroll
        for (int s = 0; s < 4; s++) {
          int kl = s * 32 + lq * 8;
          int ar = rg * 16 + lr;
          bf8v a = *(const bf8v*)((char*)abuf + ar * 256 + ((kl * 2) ^ ((ar & 7) << 4)));
          int c0 = cpair * 32 + lr, c1 = c0 + 16;
          bf8v b0 = *(const bf8v*)((char*)wbuf + c0 * 256 + ((kl * 2) ^ ((c0 & 7) << 4)));
          bf8v b1 = *(const bf8v*)((char*)wbuf + c1 * 256 + ((kl * 2) ^ ((c1 & 7) << 4)));
          acc0 = MFMA16(a, b0, acc0);
          acc1 = MFMA16(a, b1, acc1);
        }
      }
      __syncthreads();
      float* e = (float*)(sm + D4_E);
      {
        int cl0 = cpair * 32 + lr;
        if (cl0 < 125) {
#pragma unroll
          for (int r = 0; r < 4; r++)
            e[(rg * 16 + lq * 4 + r) * 129 + cl0] = acc0[r] + b_op[base + cl0];
        }
        int cl1 = cpair * 32 + 16 + lr;
        if (cl1 < 125) {
#pragma unroll
          for (int r = 0; r < 4; r++)
            e[(rg * 16 + lq * 4 + r) * 129 + cl1] = acc1[r] + b_op[base + cl1];
        }
      }
      __syncthreads();
      if (tid < 64) {
        float sm_ = 0.f, v1 = -1e30f, v2 = -1e30f;
        int i1 = 0, i2 = 0;
        for (int c2 = 0; c2 < 125; c2++) {
          float v = e[tid * 129 + c2];
          sm_ += expf(v);
          if (v > v1) { v2 = v1; i2 = i1; v1 = v; i1 = base + c2; }
          else if (v > v2) { v2 = v; i2 = base + c2; }
        }
        astf(rowsum + bid * 64 + tid, sm_);
        astf(rmax + (bid * 64 + tid) * 2 + 0, v1);
        ast((unsigned*)ridx + (bid * 64 + tid) * 2 + 0, (unsigned)i1);
        astf(rmax + (bid * 64 + tid) * 2 + 1, v2);
        ast((unsigned*)ridx + (bid * 64 + tid) * 2 + 1, (unsigned)i2);
      }
    }
    gridbar2(barsG, lgenG); lgenG++;
    // ---- P5: probs write (NT) + dedup'd candidate refine (f64) + next LSTM ----
    {
      float* psc2 = (float*)(sm + D_PSC2);
      {
        int rr = tid & 63, pp = tid >> 6;
        float s_ = 0.f;
#pragma unroll 4
        for (int cu = pp * 16; cu < pp * 16 + 16; cu++) s_ += aldf(rowsum + cu * 64 + rr);
        psc2[rr * 17 + pp] = s_;
      }
      __syncthreads();
      float* rt = (float*)(sm + D_RT);
      if (tid < 64) {
        float s_ = 0.f;
#pragma unroll
        for (int p2 = 0; p2 < 16; p2++) s_ += psc2[tid * 17 + p2];
        rt[tid] = s_;
      }
      __syncthreads();
      float* e = (float*)(sm + D4_E);
      {
        int base = bid * 125;
        for (int i = tid; i < 8000; i += 1024) {
          int r_ = i / 125, c2 = i - r_ * 125;
          float pv = expf(e[r_ * 129 + c2]) / rt[r_];
          __builtin_nontemporal_store(pv, out + ((size_t)r_ * 32 + st) * 32000 + base + c2);
        }
      }
      if (st < 31) {
        int* y_l = (int*)(sm + D_YL);
        if (cgl < 16) {
          int rowg = bg * 16 + cgl;
          float* rv = (float*)(sm + D_RV);
          float* rr2 = (float*)(sm + D_RR);
          int* ccnt = (int*)(sm + D_CCN);
          int* cand = (int*)(sm + D_CAND);
          double* rs = (double*)(sm + D_RS);
          int* rc = (int*)(sm + D_RC);
          float myv = -1e30f;
          if (tid < 512) {
            myv = aldf(rmax + ((size_t)(tid >> 1) * 64 + rowg) * 2 + (tid & 1));
            rv[tid] = myv;
            rr2[tid] = myv;
          }
          if (tid == 0) ccnt[0] = 0;
          __syncthreads();
          for (int w2 = 256; w2 >= 1; w2 >>= 1) {
            if (tid < w2) rr2[tid] = fmaxf(rr2[tid], rr2[tid + w2]);
            __syncthreads();
          }
          float thr = rr2[0] - DELTA;
          if (tid < 512 && myv >= thr) {
            int slot = atomicAdd(&ccnt[0], 1);
            if (slot < 16)
              cand[slot] = (int)ald((const unsigned*)ridx +
                                    ((size_t)(tid >> 1) * 64 + rowg) * 2 + (tid & 1));
          }
          __syncthreads();
          int cnt = ccnt[0] < 16 ? ccnt[0] : 16;
          if (wv < cnt) {
            int c = cand[wv];
            double s_ = 0.0;
            for (int k = l; k < 1024; k += 64) {
              unsigned u = ald(ahpk + (size_t)rowg * 1024 + k);
              float av = us2f((unsigned short)(u >> 16)) + us2f((unsigned short)(u & 0xffffu));
              s_ += (double)av * (double)Wout_f32[(size_t)k * 32000 + c];
            }
#pragma unroll
            for (int off = 32; off > 0; off >>= 1) s_ += __shfl_down(s_, off);
            if (l == 0) { rs[wv] = s_ + (double)b_op[c]; rc[wv] = c; }
          }
          __syncthreads();
          if (tid == 0) {
            double bv = -1e30; int bc = 0x7fffffff;
            for (int ci = 0; ci < cnt; ci++) {
              double s_ = rs[ci]; int c = rc[ci];
              if (s_ > bv || (s_ == bv && c < bc)) { bv = s_; bc = c; }
            }
            ast(ybuf + rowg, (unsigned)bc);
          }
        }
        bar64(barL, lgenL, lid); lgenL++;
        if (tid < 16) y_l[tid] = (int)ald(ybuf + bg * 16 + tid);
        __syncthreads();
        dec_lstm8(bg, cgl, tid, sm, hc, hn, dec_emb, KRh, KRl, dec_b, c_);
      }
    }
    bar64(barL, lgenL, lid); lgenL++;
    { unsigned* tp = hc; hc = hn; hn = tp; }
  }
}

// ---------------- host launch ----------------
extern "C" void kernel_launch(void* const* d_in, const int* in_sizes, int n_in,
                              void* d_out, int out_size, void* d_ws, size_t ws_size,
                              hipStream_t stream) {
  (void)in_sizes; (void)n_in; (void)out_size; (void)ws_size;
  const int*   src     = (const int*)  d_in[0];
  const float* enc_emb = (const float*)d_in[1];
  const float* enc_K   = (const float*)d_in[2];
  const float* enc_R   = (const float*)d_in[3];
  const float* enc_b   = (const float*)d_in[4];
  const float* dec_emb = (const float*)d_in[5];
  const float* dec_K   = (const float*)d_in[6];
  const float* dec_R   = (const float*)d_in[7];
  const float* dec_b   = (const float*)d_in[8];
  const float* W_a     = (const float*)d_in[9];
  const float* W_c     = (const float*)d_in[10];
  const float* b_c     = (const float*)d_in[11];
  const float* W_out   = (const float*)d_in[12];
  const float* b_out   = (const float*)d_in[13];
  char* ws = (char*)d_ws;

  hipFuncSetAttribute((const void*)ed_enc_v8, hipFuncAttributeMaxDynamicSharedMemorySize, 163840);
  hipFuncSetAttribute((const void*)ed_dec_v8, hipFuncAttributeMaxDynamicSharedMemorySize, 163840);

  bf16* KpTh = (bf16*)(ws + OKPT_H);
  bf16* KpTl = (bf16*)(ws + OKPT_L);
  bf16* RpTh = (bf16*)(ws + ORPT_H);
  bf16* RpTl = (bf16*)(ws + ORPT_L);
  bf16* xeh  = (bf16*)(ws + OXE_H);
  bf16* xel  = (bf16*)(ws + OXE_L);
  float* hsf = (float*)(ws + OHSF5);
  unsigned* hpkE0 = (unsigned*)(ws + OHPK_E0);
  unsigned* hpkE1 = (unsigned*)(ws + OHPK_E1);
  unsigned* hpkD0 = (unsigned*)(ws + OHPK_D0);
  float* cbuf = (float*)(ws + OCBUF5);
  unsigned* ahpk = (unsigned*)(ws + OAHPK);
  float* rsum = (float*)(ws + ORSUM5);
  float* rmaxp = (float*)(ws + ORMAX5);
  int*  ridxp = (int*)(ws + ORIDX5);
  float* psum = (float*)(ws + OPSUM5);
  unsigned* barsE = (unsigned*)(ws + OBARS5);
  unsigned* barsG = (unsigned*)(ws + OBARS5 + 4096);
  unsigned* barsL = (unsigned*)(ws + OBARS5 + 8192);
  unsigned* ybuf = (unsigned*)(ws + OYBUF);
  bf16* XkL  = (bf16*)(ws + OXK_L5);
  bf16* XkH  = (bf16*)d_out;
  bf16* WcTh = (bf16*)(ws + OWCT_H);
  bf16* WcTl = (bf16*)(ws + OWCT_L);
  float* pctx = (float*)(ws + OPCTX5);
  float* qbuf = (float*)(ws + OQBUF);
  bf16* WaB  = (bf16*)(ws + OWAB);
  bf16* WoTh = (bf16*)(ws + OWOT5);
  bf16* KRTh = (bf16*)(ws + OKRTH5);
  bf16* KRTl = (bf16*)(ws + OKRTL5);

  ed_zero_v8<<<512, 256, 0, stream>>>((float4*)(ws + XCH), 131072);
  ed_transpose_split_v8<<<dim3(128, 32), 256, 0, stream>>>(enc_K, KpTh, KpTl, 1024, 4096, 1024, 0, 1);
  ed_transpose_split_v8<<<dim3(128, 32), 256, 0, stream>>>(enc_R, RpTh, RpTl, 1024, 4096, 1024, 0, 1);
  ed_gather_split_v8<<<16384, 256, 0, stream>>>(src, enc_emb, xeh, xel);
  ed_gemm3_v8<<<dim3(32, 128), 256, 0, stream>>>(xeh, xel, KpTh, KpTl, XkH, XkL, 16384, 4096, 1024);
  ed_transpose_split_v8<<<dim3(32, 64), 256, 0, stream>>>(W_c, WcTh, WcTl, 2048, 1024, 2048, 0, 0);
  ed_enc_v8<<<256, 1024, 87040, stream>>>(src, RpTh, RpTl, XkH, XkL, enc_b,
                                          hpkE0, hpkE1, cbuf, hsf, barsE);
  ed_cvt_v8<<<1024, 256, 0, stream>>>(W_a, WaB, 1048576);
  ed_transpose_v8<<<dim3(1000, 32), 256, 0, stream>>>(W_out, WoTh, 1024, 32000, 1024, 0, 0);
  ed_transpose_split_v8<<<dim3(128, 32), 256, 0, stream>>>(dec_K, KRTh, KRTl, 1024, 4096, 2048, 0, 1);
  ed_transpose_split_v8<<<dim3(128, 32), 256, 0, stream>>>(dec_R, KRTh, KRTl, 1024, 4096, 2048, 1024, 1);
  ed_dec_v8<<<256, 1024, 150528, stream>>>(src, KRTh, KRTl, dec_b, WcTh, WcTl, b_c,
                                           WoTh, b_out, W_out, dec_emb, WaB, qbuf, hsf,
                                           hpkE0, hpkD0, cbuf, pctx, psum, ahpk,
                                           rsum, rmaxp, ridxp, ybuf, (float*)d_out,
                                           barsG, barsL);
}

// Round 9
// 12165.075 us; speedup vs baseline: 1.1862x; 1.0220x over previous
//
#include <hip/hip_runtime.h>
#include <hip/hip_bf16.h>

typedef __hip_bfloat16 bf16;
typedef short bf8v __attribute__((ext_vector_type(8)));   // 8 x bf16 (4 VGPR)
typedef float f32x4 __attribute__((ext_vector_type(4)));

#define DEVINL __device__ __forceinline__
#define MFMA16(a, b, c) __builtin_amdgcn_mfma_f32_16x16x32_bf16((a), (b), (c), 0, 0, 0)

DEVINL float us2f(unsigned short u) { unsigned v = ((unsigned)u) << 16; return __uint_as_float(v); }
DEVINL float b2f(bf16 x) { return __bfloat162float(x); }
DEVINL bf16 f2b(float x) { return __float2bfloat16(x); }
DEVINL float sigf(float x) { return 1.0f / (1.0f + expf(-x)); }
DEVINL unsigned short f2bu(float f) { bf16 h = __float2bfloat16(f); return *(unsigned short*)&h; }

DEVINL void gload16(const void* g, void* l) {
  __builtin_amdgcn_global_load_lds((const __attribute__((address_space(1))) void*)g,
                                   (__attribute__((address_space(3))) void*)l, 16, 0, 0);
}

// ---- relaxed agent-scope atomics ----
DEVINL unsigned ald(const unsigned* p) {
  return __hip_atomic_load(p, __ATOMIC_RELAXED, __HIP_MEMORY_SCOPE_AGENT);
}
DEVINL void ast(unsigned* p, unsigned v) {
  __hip_atomic_store(p, v, __ATOMIC_RELAXED, __HIP_MEMORY_SCOPE_AGENT);
}
DEVINL float aldf(const float* p) { unsigned u = ald((const unsigned*)p); return __uint_as_float(u); }
DEVINL void astf(float* p, float v) { ast((unsigned*)p, __float_as_uint(v)); }

// ---- XCD-pair remap: physical bid -> logical lid so lid>>6 (bg) sits on 2 XCDs ----
DEVINL int remap_lid(int bid) { return ((bid & 7) >> 1) * 64 + (((bid >> 3) << 1) | (bid & 1)); }

// ---- global 256-block barrier (8 XCD-local groups x 32), parity-buffered ----
DEVINL void gridbar2(unsigned* bars, unsigned lgen) {
  __syncthreads();
  if (threadIdx.x == 0) {
    unsigned s = lgen & 1;
    unsigned g = blockIdx.x & 7;
    unsigned* grp = bars + (g * 2 + s) * 16;
    unsigned* top = bars + (16 + s) * 16;
    unsigned* gen = bars + 288;
    unsigned t = __hip_atomic_fetch_add(grp, 1u, __ATOMIC_RELAXED, __HIP_MEMORY_SCOPE_AGENT);
    if (t == 31u) {
      ast(grp, 0u);
      unsigned tt = __hip_atomic_fetch_add(top, 1u, __ATOMIC_RELAXED, __HIP_MEMORY_SCOPE_AGENT);
      if (tt == 7u) {
        ast(top, 0u);
        asm volatile("s_waitcnt vmcnt(0)");
        ast(gen, lgen + 1u);
      }
    }
    while (ald(gen) <= lgen) __builtin_amdgcn_s_sleep(2);
  }
  __syncthreads();
}

// ---- local 64-block barrier (2 groups x 32) ----
DEVINL void bar64(unsigned* b, unsigned lgen, int lid) {
  __syncthreads();
  if (threadIdx.x == 0) {
    unsigned s = lgen & 1;
    unsigned* grp = b + (((unsigned)(lid >> 5) & 1u) * 2 + s) * 16;
    unsigned* top = b + (4 + s) * 16;
    unsigned* gen = b + 96;
    unsigned t = __hip_atomic_fetch_add(grp, 1u, __ATOMIC_RELAXED, __HIP_MEMORY_SCOPE_AGENT);
    if (t == 31u) {
      ast(grp, 0u);
      unsigned tt = __hip_atomic_fetch_add(top, 1u, __ATOMIC_RELAXED, __HIP_MEMORY_SCOPE_AGENT);
      if (tt == 1u) {
        ast(top, 0u);
        asm volatile("s_waitcnt vmcnt(0)");
        ast(gen, lgen + 1u);
      }
    }
    while (ald(gen) <= lgen) __builtin_amdgcn_s_sleep(1);
  }
  __syncthreads();
}

// ---------------- ws layout (bytes); total <= 272,629,760 ----
#define OKPT_H  ((size_t)0)
#define OKPT_L  ((size_t)8388608)
#define ORPT_H  ((size_t)16777216)
#define ORPT_L  ((size_t)25165824)
#define OXE_H   ((size_t)35651584)
#define OXE_L   ((size_t)69206016)
#define OHSF5   ((size_t)35651584)
#define XCH     ((size_t)136314880)
#define OHPK_E0 (XCH + 0)
#define OHPK_E1 (XCH + 262144)
#define OHPK_D0 (XCH + 524288)
#define OCBUF5  (XCH + 1048576)
#define OAHPK   (XCH + 1310720)
#define ORSUM5  (XCH + 1572864)
#define ORMAX5  (XCH + 1638400)
#define ORIDX5  (XCH + 1769472)
#define OPSUM5  (XCH + 1900544)
#define OBARS5  (XCH + 1901568)
#define OYBUF   (XCH + 1917952)
#define OAHB    (XCH + 1933312)
#define OXK_L5  ((size_t)138412032)
#define OWCT_H  ((size_t)0)
#define OWCT_L  ((size_t)4194304)
#define OPCTX5  ((size_t)8388608)
#define OQBUF   ORPT_H
#define OWAB    (ORPT_H + 262144)
#define OWOT5   ((size_t)138412032)
#define OKRTH5  ((size_t)203948032)
#define OKRTL5  ((size_t)220725248)

#define DELTA   1e-4f

// decoder LDS pool offsets (pool 150528)
#define D_LH   0
#define D_LL   32768
#define D_ZS   65536
#define D_KB   83968      /* double-buffered: +(c&1)*32768; hi at +0, lo at +16384 */
#define D4_A   0          /* double: +(c&1)*16384 */
#define D4_W   32768      /* double: +(c&1)*32768 -> ends 98304 */
#define D4_E   98304      /* [64][129] f32 -> ends 131328 */
#define D_WA   0
#define D_ES   65536
#define D_ZS3  0
#define D_PSC2 0
#define D_RV   8192
#define D_RR   10240
#define D_CCN  12288
#define D_CAND 12352
#define D_RS   12480
#define D_RC   12608
#define D_YL   149504
#define D_INV  149568
#define D_RT   149632

// ---------------- utility kernels ----------------
__global__ void ed_zero_v9(float4* p, int n) {
  int i = blockIdx.x * 256 + threadIdx.x;
  if (i < n) p[i] = make_float4(0.f, 0.f, 0.f, 0.f);
}

__global__ void ed_cvt_v9(const float* __restrict__ in, bf16* __restrict__ out, int n) {
  int i = (blockIdx.x * 256 + threadIdx.x) * 4;
  if (i + 3 < n) {
    float4 v = *(const float4*)(in + i);
    ushort4 o;
    o.x = f2bu(v.x); o.y = f2bu(v.y); o.z = f2bu(v.z); o.w = f2bu(v.w);
    *(ushort4*)(out + i) = o;
  }
}

__global__ void ed_transpose_v9(const float* __restrict__ in, bf16* __restrict__ out,
                                int R, int C, int ostride, int ooff, int perm) {
  __shared__ float tile[32][33];
  int c0 = blockIdx.x * 32, r0 = blockIdx.y * 32;
  int tx = threadIdx.x & 31, ty0 = threadIdx.x >> 5;
#pragma unroll
  for (int i = 0; i < 4; i++) {
    int ty = ty0 + i * 8;
    tile[ty][tx] = in[(size_t)(r0 + ty) * C + c0 + tx];
  }
  __syncthreads();
#pragma unroll
  for (int i = 0; i < 4; i++) {
    int ty = ty0 + i * 8;
    int c = c0 + ty;
    int oc = perm ? ((c & 1023) * 4 + (c >> 10)) : c;
    out[(size_t)oc * ostride + ooff + r0 + tx] = f2b(tile[tx][ty]);
  }
}

__global__ void ed_transpose_split_v9(const float* __restrict__ in, bf16* __restrict__ oh,
                                      bf16* __restrict__ ol, int R, int C, int ostride,
                                      int ooff, int perm) {
  __shared__ float tile[32][33];
  int c0 = blockIdx.x * 32, r0 = blockIdx.y * 32;
  int tx = threadIdx.x & 31, ty0 = threadIdx.x >> 5;
#pragma unroll
  for (int i = 0; i < 4; i++) {
    int ty = ty0 + i * 8;
    tile[ty][tx] = in[(size_t)(r0 + ty) * C + c0 + tx];
  }
  __syncthreads();
#pragma unroll
  for (int i = 0; i < 4; i++) {
    int ty = ty0 + i * 8;
    int c = c0 + ty;
    int oc = perm ? ((c & 1023) * 4 + (c >> 10)) : c;
    float v = tile[tx][ty];
    bf16 hh = f2b(v);
    size_t o = (size_t)oc * ostride + ooff + r0 + tx;
    oh[o] = hh;
    ol[o] = f2b(v - b2f(hh));
  }
}

__global__ void ed_gather_split_v9(const int* __restrict__ src, const float* __restrict__ emb,
                                   bf16* __restrict__ xh, bf16* __restrict__ xl) {
  int bid = blockIdx.x;
  int t = bid >> 6, b = bid & 63;
  int tok = src[b * 256 + t];
  const float* rowp = emb + (size_t)tok * 1024;
  int i = threadIdx.x * 4;
  float4 v = *(const float4*)(rowp + i);
  bf16 h0 = f2b(v.x), h1 = f2b(v.y), h2 = f2b(v.z), h3 = f2b(v.w);
  ushort4 oh, ol;
  oh.x = *(unsigned short*)&h0; oh.y = *(unsigned short*)&h1;
  oh.z = *(unsigned short*)&h2; oh.w = *(unsigned short*)&h3;
  ol.x = f2bu(v.x - b2f(h0)); ol.y = f2bu(v.y - b2f(h1));
  ol.z = f2bu(v.z - b2f(h2)); ol.w = f2bu(v.w - b2f(h3));
  *(ushort4*)(xh + (size_t)bid * 1024 + i) = oh;
  *(ushort4*)(xl + (size_t)bid * 1024 + i) = ol;
}

// ---------------- split-precision GEMM (3-term), split output (Xk) ----------------
__global__ __launch_bounds__(256, 2) void ed_gemm3_v9(
    const bf16* __restrict__ Ah, const bf16* __restrict__ Al,
    const bf16* __restrict__ Bh, const bf16* __restrict__ Bl,
    bf16* __restrict__ Ch, bf16* __restrict__ Cl, int M, int N, int K) {
  __shared__ __align__(16) bf16 Ash[128 * 32];
  __shared__ __align__(16) bf16 Asl[128 * 32];
  __shared__ __align__(16) bf16 Bsh[128 * 32];
  __shared__ __align__(16) bf16 Bsl[128 * 32];
  int m0 = blockIdx.y * 128, n0 = blockIdx.x * 128;
  int tid = threadIdx.x, w = tid >> 6, l = tid & 63;
  int wm = w >> 1, wn = w & 1;
  int lr = l & 15, lq = l >> 4;
  f32x4 acc[4][4] = {};
  for (int k0 = 0; k0 < K; k0 += 32) {
    __syncthreads();
#pragma unroll
    for (int j = 0; j < 2; j++) {
      int o = (w * 2 + j) * 1024 + l * 16;
      int rrow = o >> 6, kk = (o & 63) >> 1;
      gload16(Ah + (size_t)(m0 + rrow) * K + k0 + kk, (char*)Ash + (w * 2 + j) * 1024);
      gload16(Al + (size_t)(m0 + rrow) * K + k0 + kk, (char*)Asl + (w * 2 + j) * 1024);
      gload16(Bh + (size_t)(n0 + rrow) * K + k0 + kk, (char*)Bsh + (w * 2 + j) * 1024);
      gload16(Bl + (size_t)(n0 + rrow) * K + k0 + kk, (char*)Bsl + (w * 2 + j) * 1024);
    }
    __syncthreads();
#pragma unroll
    for (int mi = 0; mi < 4; mi++) {
      bf8v a_h = *(const bf8v*)(Ash + (wm * 64 + mi * 16 + lr) * 32 + lq * 8);
      bf8v a_l = *(const bf8v*)(Asl + (wm * 64 + mi * 16 + lr) * 32 + lq * 8);
#pragma unroll
      for (int ni = 0; ni < 4; ni++) {
        bf8v b_h = *(const bf8v*)(Bsh + (wn * 64 + ni * 16 + lr) * 32 + lq * 8);
        bf8v b_l = *(const bf8v*)(Bsl + (wn * 64 + ni * 16 + lr) * 32 + lq * 8);
        acc[mi][ni] = MFMA16(a_h, b_h, acc[mi][ni]);
        acc[mi][ni] = MFMA16(a_h, b_l, acc[mi][ni]);
        acc[mi][ni] = MFMA16(a_l, b_h, acc[mi][ni]);
      }
    }
  }
#pragma unroll
  for (int mi = 0; mi < 4; mi++)
#pragma unroll
    for (int ni = 0; ni < 4; ni++)
#pragma unroll
      for (int r = 0; r < 4; r++) {
        float v = acc[mi][ni][r];
        bf16 hh = f2b(v);
        size_t idx = (size_t)(m0 + wm * 64 + mi * 16 + lq * 4 + r) * N + n0 + wn * 64 + ni * 16 + lr;
        Ch[idx] = hh;
        Cl[idx] = f2b(v - b2f(hh));
      }
}

// ---------------- encoder: XCD-pair remap; per-bg local barriers ----------------
__global__ __launch_bounds__(1024, 4) void ed_enc_v9(
    const int* __restrict__ src, const bf16* __restrict__ Rh, const bf16* __restrict__ Rl,
    const bf16* __restrict__ Xh, const bf16* __restrict__ Xl, const float* __restrict__ enc_b,
    unsigned* hpk0, unsigned* hpk1, float* __restrict__ cbuf,
    float* __restrict__ hsf, unsigned* barsE) {
  extern __shared__ char sm[];
  bf16* lh = (bf16*)sm;
  bf16* ll = (bf16*)(sm + 32768);
  float* zs = (float*)(sm + 65536);
  float* xkf = (float*)(sm + 82944);
  int bid = blockIdx.x, tid = threadIdx.x;
  int lid_all = remap_lid(bid);
  int bg = lid_all >> 6, cg = lid_all & 63, lid = lid_all & 63;
  unsigned* barL = barsE + bg * 128;
  int wv = tid >> 6, l = tid & 63, lr = l & 15, lq = l >> 4;
  int kq = wv >> 2, cs = wv & 3;
  int srow = tid >> 6, sj0 = (tid & 63) * 16;
  int grow = tid >> 4, gul = tid & 15;
  bf8v Rh_[8], Rl_[8];
  {
    const bf16* bh = Rh + (size_t)(cg * 64 + cs * 16 + lr) * 1024 + kq * 256 + lq * 8;
    const bf16* bl = Rl + (size_t)(cg * 64 + cs * 16 + lr) * 1024 + kq * 256 + lq * 8;
#pragma unroll
    for (int i = 0; i < 8; i++) {
      Rh_[i] = *(const bf8v*)(bh + i * 32);
      Rl_[i] = *(const bf8v*)(bl + i * 32);
    }
  }
  float bi[4];
  float c_ = 0.f;
  if (tid < 256) {
#pragma unroll
    for (int g = 0; g < 4; g++) {
      int colp = cg * 64 + gul * 4 + g;
      bi[g] = enc_b[(colp & 3) * 1024 + (colp >> 2)];
    }
  }
  unsigned *hc = hpk0, *hn = hpk1;
  unsigned lgen = 0;
  for (int t = 0; t < 256; t++) {
    {
      const unsigned* hrow = hc + (size_t)(bg * 16 + srow) * 1024 + sj0;
      unsigned u[16];
#pragma unroll
      for (int j = 0; j < 16; j++) u[j] = ald(hrow + j);
      int r8 = (srow & 7) << 3;
#pragma unroll
      for (int j = 0; j < 16; j += 2) {
        int es = (sj0 + j) ^ r8;
        *(unsigned*)((char*)lh + srow * 2048 + es * 2) = (u[j] >> 16) | (u[j + 1] & 0xffff0000u);
        *(unsigned*)((char*)ll + srow * 2048 + es * 2) = (u[j] & 0xffffu) | (u[j + 1] << 16);
      }
    }
    {
      int xr = tid >> 6, xc = tid & 63;
      size_t xi = ((size_t)t * 64 + bg * 16 + xr) * 4096 + cg * 64 + xc;
      unsigned short xh = __builtin_nontemporal_load((const unsigned short*)(Xh + xi));
      unsigned short xl = __builtin_nontemporal_load((const unsigned short*)(Xl + xi));
      xkf[xr * 64 + xc] = us2f(xh) + us2f(xl);
    }
    __syncthreads();
    {
      f32x4 acc = {0.f, 0.f, 0.f, 0.f};
      int r8 = (lr & 7) << 3;
#pragma unroll
      for (int i = 0; i < 8; i++) {
        int e0 = kq * 256 + i * 32 + lq * 8;
        int es = e0 ^ r8;
        bf8v a_h = *(const bf8v*)((char*)lh + lr * 2048 + es * 2);
        bf8v a_l = *(const bf8v*)((char*)ll + lr * 2048 + es * 2);
        acc = MFMA16(a_h, Rh_[i], acc);
        acc = MFMA16(a_h, Rl_[i], acc);
        acc = MFMA16(a_l, Rh_[i], acc);
        acc = MFMA16(a_l, Rl_[i], acc);
      }
#pragma unroll
      for (int r = 0; r < 4; r++) zs[(kq * 16 + lq * 4 + r) * 68 + cs * 16 + lr] = acc[r];
    }
    __syncthreads();
    if (tid < 256) {
      int b_ = bg * 16 + grow, u = cg * 16 + gul;
      float zz[4];
#pragma unroll
      for (int g = 0; g < 4; g++) {
        int cc = gul * 4 + g;
        zz[g] = zs[(0 + grow) * 68 + cc] + zs[(16 + grow) * 68 + cc] +
                zs[(32 + grow) * 68 + cc] + zs[(48 + grow) * 68 + cc] +
                xkf[grow * 64 + cc] + bi[g];
      }
      float iv = sigf(zz[0]), fv = sigf(zz[1]), gv = tanhf(zz[2]), ov = sigf(zz[3]);
      float cn = fv * c_ + iv * gv;
      float hnv = ov * tanhf(cn);
      bool m = src[b_ * 256 + t] > 0;
      int es = u ^ ((grow & 7) << 3);
      float hold = b2f(*(const bf16*)((char*)lh + grow * 2048 + es * 2)) +
                   b2f(*(const bf16*)((char*)ll + grow * 2048 + es * 2));
      float hv = m ? hnv : hold;
      c_ = m ? cn : c_;
      unsigned short uh = f2bu(hv);
      unsigned pkv = ((unsigned)uh << 16) | (unsigned)f2bu(hv - us2f(uh));
      ast(hn + (size_t)b_ * 1024 + u, pkv);
      hsf[((size_t)t * 64 + b_) * 1024 + u] = hv;
    }
    bar64(barL, lgen, lid);
    lgen++;
    unsigned* tp = hc; hc = hn; hn = tp;
  }
  if (tid < 256) cbuf[(size_t)(bg * 16 + grow) * 1024 + cg * 16 + gul] = c_;
}

// ---------------- decoder LSTM (pipelined KRT staging, counted vmcnt) ----------------
DEVINL void dec_lstm9(int bg, int cgl, int tid, char* sm,
                      const unsigned* hc, unsigned* hn,
                      const float* __restrict__ dec_emb,
                      const bf16* __restrict__ Kh, const bf16* __restrict__ Kl,
                      const float* __restrict__ dec_b, float& c_) {
  bf16* lh = (bf16*)(sm + D_LH);
  bf16* ll = (bf16*)(sm + D_LL);
  int wv = tid >> 6, l = tid & 63, lr = l & 15, lq = l >> 4;
  int kg2 = wv >> 2, cs = wv & 3;
  const int* y_l = (const int*)(sm + D_YL);
  float* zs = (float*)(sm + D_ZS);
  // stage h -> swizzled LDS
  {
    int srow = tid >> 6, sl = tid & 63;
    const unsigned* hrow = hc + (size_t)(bg * 16 + srow) * 1024 + sl * 16;
    unsigned u[16];
#pragma unroll
    for (int j = 0; j < 16; j++) u[j] = ald(hrow + j);
    uint4 ha, hb, la, lb;
    ha.x = (u[0] >> 16) | (u[1] & 0xffff0000u);  ha.y = (u[2] >> 16) | (u[3] & 0xffff0000u);
    ha.z = (u[4] >> 16) | (u[5] & 0xffff0000u);  ha.w = (u[6] >> 16) | (u[7] & 0xffff0000u);
    hb.x = (u[8] >> 16) | (u[9] & 0xffff0000u);  hb.y = (u[10] >> 16) | (u[11] & 0xffff0000u);
    hb.z = (u[12] >> 16) | (u[13] & 0xffff0000u); hb.w = (u[14] >> 16) | (u[15] & 0xffff0000u);
    la.x = (u[0] & 0xffffu) | (u[1] << 16);  la.y = (u[2] & 0xffffu) | (u[3] << 16);
    la.z = (u[4] & 0xffffu) | (u[5] << 16);  la.w = (u[6] & 0xffffu) | (u[7] << 16);
    lb.x = (u[8] & 0xffffu) | (u[9] << 16);  lb.y = (u[10] & 0xffffu) | (u[11] << 16);
    lb.z = (u[12] & 0xffffu) | (u[13] << 16); lb.w = (u[14] & 0xffffu) | (u[15] << 16);
    int swz = (srow & 7) << 4;
    char* rbh = (char*)lh + srow * 2048;
    char* rbl = (char*)ll + srow * 2048;
    *(uint4*)(rbh + ((sl * 32) ^ swz)) = ha;
    *(uint4*)(rbh + ((sl * 32 + 16) ^ swz)) = hb;
    *(uint4*)(rbl + ((sl * 32) ^ swz)) = la;
    *(uint4*)(rbl + ((sl * 32 + 16) ^ swz)) = lb;
  }
  // preload x = dec_emb row fragments into registers (chunks 0..7)
  bf8v xah[8], xal[8];
  {
    const float* xr = dec_emb + (size_t)y_l[lr] * 1024 + kg2 * 32 + lq * 8;
#pragma unroll
    for (int c = 0; c < 8; c++) {
      float4 v0 = *(const float4*)(xr + c * 128);
      float4 v1 = *(const float4*)(xr + c * 128 + 4);
      float vs[8] = {v0.x, v0.y, v0.z, v0.w, v1.x, v1.y, v1.z, v1.w};
#pragma unroll
      for (int e = 0; e < 8; e++) {
        unsigned short uh = f2bu(vs[e]);
        xah[c][e] = (short)uh;
        xal[c][e] = (short)f2bu(vs[e] - us2f(uh));
      }
    }
  }
  auto issueKB = [&](int c) {
    int i = wv * 64 + l;
    int col = i >> 4, j = i & 15;
    size_t se = (size_t)(cgl * 64 + col) * 2048 + c * 128 + ((size_t)(j ^ (col & 7)) << 3);
    char* dst = (char*)sm + D_KB + (c & 1) * 32768 + wv * 1024;
    gload16(Kh + se, dst);
    gload16(Kl + se, dst + 16384);
  };
  issueKB(0);
  issueKB(1);
  __syncthreads();  // h+x staged; kb0/kb1 drained
  f32x4 acc = {0.f, 0.f, 0.f, 0.f};
  int colB = cs * 16 + lr;
  int bswz = (colB & 7) << 4;
  int aswz = (lr & 7) << 4;
#pragma unroll
  for (int c = 0; c < 16; c++) {
    if (c < 15) asm volatile("s_waitcnt vmcnt(2)" ::: "memory");
    else        asm volatile("s_waitcnt vmcnt(0)" ::: "memory");
    __builtin_amdgcn_s_barrier();
    __builtin_amdgcn_sched_barrier(0);
    {
      int kl = kg2 * 32 + lq * 8;
      const char* kb = (const char*)sm + D_KB + (c & 1) * 32768;
      bf8v b_h = *(const bf8v*)(kb + colB * 256 + ((kl * 2) ^ bswz));
      bf8v b_l = *(const bf8v*)(kb + 16384 + colB * 256 + ((kl * 2) ^ bswz));
      bf8v a_h, a_l;
      if (c < 8) {
        a_h = xah[c];
        a_l = xal[c];
      } else {
        int hk = (c - 8) * 128 + kl;
        a_h = *(const bf8v*)((char*)lh + lr * 2048 + ((hk * 2) ^ aswz));
        a_l = *(const bf8v*)((char*)ll + lr * 2048 + ((hk * 2) ^ aswz));
      }
      acc = MFMA16(a_h, b_h, acc);
      acc = MFMA16(a_h, b_l, acc);
      acc = MFMA16(a_l, b_h, acc);
      acc = MFMA16(a_l, b_l, acc);
    }
    __builtin_amdgcn_sched_barrier(0);
    __builtin_amdgcn_s_barrier();
    __builtin_amdgcn_sched_barrier(0);
    if (c + 2 < 16) issueKB(c + 2);
  }
#pragma unroll
  for (int r = 0; r < 4; r++) zs[(kg2 * 16 + lq * 4 + r) * 68 + cs * 16 + lr] = acc[r];
  __syncthreads();
  if (tid < 256) {
    int grow = tid >> 4, gul = tid & 15;
    int b_ = bg * 16 + grow;
    float zz[4];
#pragma unroll
    for (int g = 0; g < 4; g++) {
      int cc = gul * 4 + g;
      int colp = cgl * 64 + cc;
      float v = zs[(0 + grow) * 68 + cc] + zs[(16 + grow) * 68 + cc] +
                zs[(32 + grow) * 68 + cc] + zs[(48 + grow) * 68 + cc];
      zz[g] = v + dec_b[(colp & 3) * 1024 + (colp >> 2)];
    }
    float iv = sigf(zz[0]), fv = sigf(zz[1]), gv = tanhf(zz[2]), ov = sigf(zz[3]);
    float cn = fv * c_ + iv * gv;
    c_ = cn;
    float hv = ov * tanhf(cn);
    unsigned short uh = f2bu(hv);
    unsigned pkv = ((unsigned)uh << 16) | (unsigned)f2bu(hv - us2f(uh));
    ast(hn + (size_t)b_ * 1024 + cgl * 16 + gul, pkv);
  }
}

// ---------------- decoder persistent kernel ----------------
__global__ __launch_bounds__(1024, 4) void ed_dec_v9(
    const int* __restrict__ src,
    const bf16* __restrict__ KRh, const bf16* __restrict__ KRl, const float* __restrict__ dec_b,
    const bf16* __restrict__ WcTh, const bf16* __restrict__ WcTl, const float* __restrict__ b_cp,
    const bf16* __restrict__ WoTh, const float* __restrict__ b_op,
    const float* __restrict__ Wout_f32, const float* __restrict__ dec_emb,
    const bf16* __restrict__ WaB, float* __restrict__ qbuf,
    const float* __restrict__ hsf,
    unsigned* hpkA, unsigned* hpkB, float* __restrict__ cbuf,
    float* __restrict__ pctx, float* __restrict__ psum, unsigned* ahpk, unsigned* ahb32,
    float* __restrict__ rowsum, float* __restrict__ rmax, int* __restrict__ ridx,
    unsigned* ybuf, float* __restrict__ out, unsigned* barsG, unsigned* barsL) {
  extern __shared__ char sm[];
  int bid = blockIdx.x, tid = threadIdx.x;
  int lid_all = remap_lid(bid);
  int bg = lid_all >> 6, cgl = lid_all & 63, lid = lid_all & 63;
  unsigned* barL = barsL + bg * 128;
  int wv = tid >> 6, l = tid & 63, lr = l & 15, lq = l >> 4;
  float c_ = 0.f;
  if (tid < 256) c_ = cbuf[(size_t)(bg * 16 + (tid >> 4)) * 1024 + cgl * 16 + (tid & 15)];
  unsigned *hc = hpkA, *hn = hpkB;
  unsigned lgenL = 0, lgenG = 0;

  if (tid < 16) ((int*)(sm + D_YL))[tid] = 1;
  __syncthreads();
  dec_lstm9(bg, cgl, tid, sm, hc, hn, dec_emb, KRh, KRl, dec_b, c_);
  bar64(barL, lgenL, lid); lgenL++;
  { unsigned* tp = hc; hc = hn; hn = tp; }

  int p4base = lid_all * 125;
  auto issueW4 = [&](int c) {
#pragma unroll
    for (int r = 0; r < 2; r++) {
      int i = wv * 128 + r * 64 + l;
      int col = i >> 4, j = i & 15;
      int ccol = col < 125 ? col : 124;
      size_t se = (size_t)(p4base + ccol) * 1024 + c * 128 + ((size_t)(j ^ (col & 7)) << 3);
      gload16(WoTh + se, (char*)sm + D4_W + (c & 1) * 32768 + wv * 2048 + r * 1024);
    }
  };
  auto stageA4 = [&](int ca) {
    int row = tid >> 4, l16 = tid & 15;
    const unsigned* ap = ahb32 + (size_t)row * 512 + ca * 64 + l16 * 4;
    uint4 hv;
    hv.x = ald(ap); hv.y = ald(ap + 1); hv.z = ald(ap + 2); hv.w = ald(ap + 3);
    *(uint4*)((char*)sm + D4_A + (ca & 1) * 16384 + row * 256 + ((l16 ^ (row & 7)) << 4)) = hv;
  };

  for (int st = 0; st < 32; st++) {
    // ---- PQ: q[b] = W_a @ h[b] (bf16 W_a); active blocks cgl<16 ----
    if (cgl < 16) {
      int colb = cgl * 64;
      int kq = wv >> 2, nq = wv & 3;
      float* zs = (float*)(sm + D_ZS);
      f32x4 acc = {0.f, 0.f, 0.f, 0.f};
      const unsigned* hrow = hc + (size_t)(bg * 16 + lr) * 1024;
      const bf16* warow = WaB + (size_t)(colb + nq * 16 + lr) * 1024;
#pragma unroll
      for (int i = 0; i < 8; i++) {
        int k = kq * 256 + i * 32 + lq * 8;
        bf8v a;
        const unsigned* hp = hrow + k;
#pragma unroll
        for (int e = 0; e < 8; e++) a[e] = (short)(ald(hp + e) >> 16);
        bf8v b = *(const bf8v*)(warow + k);
        acc = MFMA16(a, b, acc);
      }
#pragma unroll
      for (int r = 0; r < 4; r++) zs[(kq * 16 + lq * 4 + r) * 68 + nq * 16 + lr] = acc[r];
      __syncthreads();
      {
        int mrow = tid >> 6, col = tid & 63;
        float v = zs[(0 + mrow) * 68 + col] + zs[(16 + mrow) * 68 + col] +
                  zs[(32 + mrow) * 68 + col] + zs[(48 + mrow) * 68 + col];
        astf(qbuf + (size_t)(bg * 16 + mrow) * 1024 + colb + col, v);
      }
    }
    bar64(barL, lgenL, lid); lgenL++;
    // ---- P1: fused scores+ctx, single pass over hsf; block = (b, kg) ----
    {
      int b_ = lid_all >> 2, kg = lid_all & 3;
      float* wacc = (float*)(sm + D_WA);
      float* es = (float*)(sm + D_ES);
      float qr[16];
      {
        const float* qb = qbuf + (size_t)b_ * 1024 + l * 16;
        *(float4*)&qr[0]  = *(const float4*)(qb);
        *(float4*)&qr[4]  = *(const float4*)(qb + 4);
        *(float4*)&qr[8]  = *(const float4*)(qb + 8);
        *(float4*)&qr[12] = *(const float4*)(qb + 12);
      }
      float a16[16];
#pragma unroll
      for (int j = 0; j < 16; j++) a16[j] = 0.f;
      float esum = 0.f;
#pragma unroll
      for (int i = 0; i < 4; i++) {
        int kglob = kg * 64 + wv * 4 + i;
        const float* hrow = hsf + ((size_t)kglob * 64 + b_) * 1024 + l * 16;
        float4 v0 = *(const float4*)hrow;
        float4 v1 = *(const float4*)(hrow + 4);
        float4 v2 = *(const float4*)(hrow + 8);
        float4 v3 = *(const float4*)(hrow + 12);
        float vv[16] = {v0.x, v0.y, v0.z, v0.w, v1.x, v1.y, v1.z, v1.w,
                        v2.x, v2.y, v2.z, v2.w, v3.x, v3.y, v3.z, v3.w};
        float p = 0.f;
#pragma unroll
        for (int j = 0; j < 16; j++) p += qr[j] * vv[j];
#pragma unroll
        for (int off = 32; off > 0; off >>= 1) p += __shfl_xor(p, off);
        float e = (src[b_ * 256 + kglob] > 0) ? expf(p) : 0.f;
        esum += e;
#pragma unroll
        for (int j = 0; j < 16; j++) a16[j] += e * vv[j];
      }
#pragma unroll
      for (int j = 0; j < 16; j++) wacc[wv * 1024 + j * 64 + l] = a16[j];
      if (l == 0) es[wv] = esum;
      __syncthreads();
      {
        float v = 0.f;
#pragma unroll
        for (int w2 = 0; w2 < 16; w2++) v += wacc[w2 * 1024 + tid];
        int logical = (tid & 63) * 16 + (tid >> 6);
        astf(pctx + ((size_t)kg * 64 + b_) * 1024 + logical, v);
      }
      if (tid == 0) {
        float s_ = 0.f;
#pragma unroll
        for (int w2 = 0; w2 < 16; w2++) s_ += es[w2];
        astf(psum + kg * 64 + b_, s_);
      }
    }
    bar64(barL, lgenL, lid); lgenL++;
    // ---- P3: ctx-reduce + ah = tanh([ctx,h]@W_c + b_c); block = (bg, 16-col) ----
    {
      float* inv_l = (float*)(sm + D_INV);
      if (tid < 16) {
        int rb = bg * 16 + tid;
        float sg = aldf(psum + rb) + aldf(psum + 64 + rb) +
                   aldf(psum + 128 + rb) + aldf(psum + 192 + rb);
        inv_l[tid] = 1.0f / sg;
      }
      __syncthreads();
      float* zs3 = (float*)(sm + D_ZS3);
      {
        int kq = wv;
        f32x4 acc = {0.f, 0.f, 0.f, 0.f};
        const bf16* bh = WcTh + (size_t)(cgl * 16 + lr) * 2048;
        const bf16* bl = WcTl + (size_t)(cgl * 16 + lr) * 2048;
        float inv = inv_l[lr];
#pragma unroll
        for (int i = 0; i < 4; i++) {
          int k = kq * 128 + i * 32 + lq * 8;
          bf8v a_h, a_l;
          if (k < 1024) {
            const float* p0 = pctx + (size_t)(bg * 16 + lr) * 1024 + k;
#pragma unroll
            for (int e = 0; e < 8; e++) {
              float v = (aldf(p0 + e) + aldf(p0 + 65536 + e) +
                         aldf(p0 + 131072 + e) + aldf(p0 + 196608 + e)) * inv;
              unsigned short uh = f2bu(v);
              a_h[e] = (short)uh;
              a_l[e] = (short)f2bu(v - us2f(uh));
            }
          } else {
            const unsigned* hp = hc + (size_t)(bg * 16 + lr) * 1024 + (k - 1024);
#pragma unroll
            for (int e = 0; e < 8; e++) {
              unsigned u = ald(hp + e);
              a_h[e] = (short)(u >> 16);
              a_l[e] = (short)(u & 0xffffu);
            }
          }
          bf8v b_h = *(const bf8v*)(bh + k);
          bf8v b_l = *(const bf8v*)(bl + k);
          acc = MFMA16(a_h, b_h, acc); acc = MFMA16(a_h, b_l, acc);
          acc = MFMA16(a_l, b_h, acc); acc = MFMA16(a_l, b_l, acc);
        }
#pragma unroll
        for (int r = 0; r < 4; r++) zs3[(kq * 16 + lq * 4 + r) * 17 + lr] = acc[r];
      }
      __syncthreads();
      if (tid < 256) {
        int grow = tid >> 4, gcol = tid & 15;
        float v = 0.f;
#pragma unroll
        for (int q = 0; q < 16; q++) v += zs3[(q * 16 + grow) * 17 + gcol];
        v += b_cp[cgl * 16 + gcol];
        float ahv = tanhf(v);
        unsigned short uh = f2bu(ahv);
        unsigned pkv = ((unsigned)uh << 16) | (unsigned)f2bu(ahv - us2f(uh));
        ast(ahpk + (size_t)(bg * 16 + grow) * 1024 + cgl * 16 + gcol, pkv);
        float ahn = __shfl_down(ahv, 1);
        if ((tid & 1) == 0) {
          unsigned pk2 = (unsigned)f2bu(ahv) | ((unsigned)f2bu(ahn) << 16);
          ast(ahb32 + (size_t)(bg * 16 + grow) * 512 + cgl * 8 + (gcol >> 1), pk2);
        }
      }
    }
    // prefetch W chunks 0,1 into LDS; they drain during the global barrier
    issueW4(0);
    issueW4(1);
    gridbar2(barsG, lgenG); lgenG++;
    // ---- P4: pipelined logits (W dbuf + A dbuf, counted vmcnt) ----
    {
      stageA4(0);
      __syncthreads();
      int rg = wv >> 2, cpair = wv & 3;
      f32x4 acc0 = {0.f, 0.f, 0.f, 0.f}, acc1 = {0.f, 0.f, 0.f, 0.f};
#pragma unroll
      for (int c = 0; c < 8; c++) {
        if (c < 7) asm volatile("s_waitcnt vmcnt(2)" ::: "memory");
        else       asm volatile("s_waitcnt vmcnt(0)" ::: "memory");
        __builtin_amdgcn_s_barrier();
        __builtin_amdgcn_sched_barrier(0);
        {
          const char* wb = (const char*)sm + D4_W + (c & 1) * 32768;
          const char* ab = (const char*)sm + D4_A + (c & 1) * 16384;
          int ar = rg * 16 + lr;
          int c0 = cpair * 32 + lr, c1 = c0 + 16;
#pragma unroll
          for (int s = 0; s < 4; s++) {
            int kl = s * 32 + lq * 8;
            bf8v a = *(const bf8v*)(ab + ar * 256 + (((s * 4 + lq) ^ (ar & 7)) << 4));
            bf8v b0 = *(const bf8v*)(wb + c0 * 256 + ((kl * 2) ^ ((c0 & 7) << 4)));
            bf8v b1 = *(const bf8v*)(wb + c1 * 256 + ((kl * 2) ^ ((c1 & 7) << 4)));
            acc0 = MFMA16(a, b0, acc0);
            acc1 = MFMA16(a, b1, acc1);
          }
        }
        if (c < 7) stageA4(c + 1);
        asm volatile("s_waitcnt lgkmcnt(0)" ::: "memory");
        __builtin_amdgcn_sched_barrier(0);
        __builtin_amdgcn_s_barrier();
        __builtin_amdgcn_sched_barrier(0);
        if (c + 2 < 8) issueW4(c + 2);
      }
      __syncthreads();
      float* e = (float*)(sm + D4_E);
      {
        int cl0 = cpair * 32 + lr;
        if (cl0 < 125) {
#pragma unroll
          for (int r = 0; r < 4; r++)
            e[(rg * 16 + lq * 4 + r) * 129 + cl0] = acc0[r] + b_op[p4base + cl0];
        }
        int cl1 = cpair * 32 + 16 + lr;
        if (cl1 < 125) {
#pragma unroll
          for (int r = 0; r < 4; r++)
            e[(rg * 16 + lq * 4 + r) * 129 + cl1] = acc1[r] + b_op[p4base + cl1];
        }
      }
      __syncthreads();
      if (tid < 64) {
        float sm_ = 0.f, v1 = -1e30f, v2 = -1e30f;
        int i1 = 0, i2 = 0;
        for (int c2 = 0; c2 < 125; c2++) {
          float v = e[tid * 129 + c2];
          sm_ += expf(v);
          if (v > v1) { v2 = v1; i2 = i1; v1 = v; i1 = p4base + c2; }
          else if (v > v2) { v2 = v; i2 = p4base + c2; }
        }
        astf(rowsum + lid_all * 64 + tid, sm_);
        astf(rmax + (lid_all * 64 + tid) * 2 + 0, v1);
        ast((unsigned*)ridx + (lid_all * 64 + tid) * 2 + 0, (unsigned)i1);
        astf(rmax + (lid_all * 64 + tid) * 2 + 1, v2);
        ast((unsigned*)ridx + (lid_all * 64 + tid) * 2 + 1, (unsigned)i2);
      }
    }
    gridbar2(barsG, lgenG); lgenG++;
    // ---- P5: probs write (NT) + dedup'd candidate refine (f64) + next LSTM ----
    {
      float* psc2 = (float*)(sm + D_PSC2);
      {
        int rr = tid & 63, pp = tid >> 6;
        float s_ = 0.f;
#pragma unroll 4
        for (int cu = pp * 16; cu < pp * 16 + 16; cu++) s_ += aldf(rowsum + cu * 64 + rr);
        psc2[rr * 17 + pp] = s_;
      }
      __syncthreads();
      float* rt = (float*)(sm + D_RT);
      if (tid < 64) {
        float s_ = 0.f;
#pragma unroll
        for (int p2 = 0; p2 < 16; p2++) s_ += psc2[tid * 17 + p2];
        rt[tid] = s_;
      }
      __syncthreads();
      float* e = (float*)(sm + D4_E);
      {
        for (int i = tid; i < 8000; i += 1024) {
          int r_ = i / 125, c2 = i - r_ * 125;
          float pv = expf(e[r_ * 129 + c2]) / rt[r_];
          __builtin_nontemporal_store(pv, out + ((size_t)r_ * 32 + st) * 32000 + p4base + c2);
        }
      }
      if (st < 31) {
        int* y_l = (int*)(sm + D_YL);
        if (cgl < 16) {
          int rowg = bg * 16 + cgl;
          float* rv = (float*)(sm + D_RV);
          float* rr2 = (float*)(sm + D_RR);
          int* ccnt = (int*)(sm + D_CCN);
          int* cand = (int*)(sm + D_CAND);
          double* rs = (double*)(sm + D_RS);
          int* rc = (int*)(sm + D_RC);
          float myv = -1e30f;
          if (tid < 512) {
            myv = aldf(rmax + ((size_t)(tid >> 1) * 64 + rowg) * 2 + (tid & 1));
            rv[tid] = myv;
            rr2[tid] = myv;
          }
          if (tid == 0) ccnt[0] = 0;
          __syncthreads();
          for (int w2 = 256; w2 >= 1; w2 >>= 1) {
            if (tid < w2) rr2[tid] = fmaxf(rr2[tid], rr2[tid + w2]);
            __syncthreads();
          }
          float thr = rr2[0] - DELTA;
          if (tid < 512 && myv >= thr) {
            int slot = atomicAdd(&ccnt[0], 1);
            if (slot < 16)
              cand[slot] = (int)ald((const unsigned*)ridx +
                                    ((size_t)(tid >> 1) * 64 + rowg) * 2 + (tid & 1));
          }
          __syncthreads();
          int cnt = ccnt[0] < 16 ? ccnt[0] : 16;
          if (wv < cnt) {
            int c = cand[wv];
            double s_ = 0.0;
            for (int k = l; k < 1024; k += 64) {
              unsigned u = ald(ahpk + (size_t)rowg * 1024 + k);
              float av = us2f((unsigned short)(u >> 16)) + us2f((unsigned short)(u & 0xffffu));
              s_ += (double)av * (double)Wout_f32[(size_t)k * 32000 + c];
            }
#pragma unroll
            for (int off = 32; off > 0; off >>= 1) s_ += __shfl_down(s_, off);
            if (l == 0) { rs[wv] = s_ + (double)b_op[c]; rc[wv] = c; }
          }
          __syncthreads();
          if (tid == 0) {
            double bv = -1e30; int bc = 0x7fffffff;
            for (int ci = 0; ci < cnt; ci++) {
              double s_ = rs[ci]; int c = rc[ci];
              if (s_ > bv || (s_ == bv && c < bc)) { bv = s_; bc = c; }
            }
            ast(ybuf + rowg, (unsigned)bc);
          }
        }
        bar64(barL, lgenL, lid); lgenL++;
        if (tid < 16) y_l[tid] = (int)ald(ybuf + bg * 16 + tid);
        __syncthreads();
        dec_lstm9(bg, cgl, tid, sm, hc, hn, dec_emb, KRh, KRl, dec_b, c_);
      }
    }
    bar64(barL, lgenL, lid); lgenL++;
    { unsigned* tp = hc; hc = hn; hn = tp; }
  }
}

// ---------------- host launch ----------------
extern "C" void kernel_launch(void* const* d_in, const int* in_sizes, int n_in,
                              void* d_out, int out_size, void* d_ws, size_t ws_size,
                              hipStream_t stream) {
  (void)in_sizes; (void)n_in; (void)out_size; (void)ws_size;
  const int*   src     = (const int*)  d_in[0];
  const float* enc_emb = (const float*)d_in[1];
  const float* enc_K   = (const float*)d_in[2];
  const float* enc_R   = (const float*)d_in[3];
  const float* enc_b   = (const float*)d_in[4];
  const float* dec_emb = (const float*)d_in[5];
  const float* dec_K   = (const float*)d_in[6];
  const float* dec_R   = (const float*)d_in[7];
  const float* dec_b   = (const float*)d_in[8];
  const float* W_a     = (const float*)d_in[9];
  const float* W_c     = (const float*)d_in[10];
  const float* b_c     = (const float*)d_in[11];
  const float* W_out   = (const float*)d_in[12];
  const float* b_out   = (const float*)d_in[13];
  char* ws = (char*)d_ws;

  hipFuncSetAttribute((const void*)ed_enc_v9, hipFuncAttributeMaxDynamicSharedMemorySize, 163840);
  hipFuncSetAttribute((const void*)ed_dec_v9, hipFuncAttributeMaxDynamicSharedMemorySize, 163840);

  bf16* KpTh = (bf16*)(ws + OKPT_H);
  bf16* KpTl = (bf16*)(ws + OKPT_L);
  bf16* RpTh = (bf16*)(ws + ORPT_H);
  bf16* RpTl = (bf16*)(ws + ORPT_L);
  bf16* xeh  = (bf16*)(ws + OXE_H);
  bf16* xel  = (bf16*)(ws + OXE_L);
  float* hsf = (float*)(ws + OHSF5);
  unsigned* hpkE0 = (unsigned*)(ws + OHPK_E0);
  unsigned* hpkE1 = (unsigned*)(ws + OHPK_E1);
  unsigned* hpkD0 = (unsigned*)(ws + OHPK_D0);
  float* cbuf = (float*)(ws + OCBUF5);
  unsigned* ahpk = (unsigned*)(ws + OAHPK);
  unsigned* ahb32 = (unsigned*)(ws + OAHB);
  float* rsum = (float*)(ws + ORSUM5);
  float* rmaxp = (float*)(ws + ORMAX5);
  int*  ridxp = (int*)(ws + ORIDX5);
  float* psum = (float*)(ws + OPSUM5);
  unsigned* barsE = (unsigned*)(ws + OBARS5);
  unsigned* barsG = (unsigned*)(ws + OBARS5 + 4096);
  unsigned* barsL = (unsigned*)(ws + OBARS5 + 8192);
  unsigned* ybuf = (unsigned*)(ws + OYBUF);
  bf16* XkL  = (bf16*)(ws + OXK_L5);
  bf16* XkH  = (bf16*)d_out;
  bf16* WcTh = (bf16*)(ws + OWCT_H);
  bf16* WcTl = (bf16*)(ws + OWCT_L);
  float* pctx = (float*)(ws + OPCTX5);
  float* qbuf = (float*)(ws + OQBUF);
  bf16* WaB  = (bf16*)(ws + OWAB);
  bf16* WoTh = (bf16*)(ws + OWOT5);
  bf16* KRTh = (bf16*)(ws + OKRTH5);
  bf16* KRTl = (bf16*)(ws + OKRTL5);

  ed_zero_v9<<<512, 256, 0, stream>>>((float4*)(ws + XCH), 131072);
  ed_transpose_split_v9<<<dim3(128, 32), 256, 0, stream>>>(enc_K, KpTh, KpTl, 1024, 4096, 1024, 0, 1);
  ed_transpose_split_v9<<<dim3(128, 32), 256, 0, stream>>>(enc_R, RpTh, RpTl, 1024, 4096, 1024, 0, 1);
  ed_gather_split_v9<<<16384, 256, 0, stream>>>(src, enc_emb, xeh, xel);
  ed_gemm3_v9<<<dim3(32, 128), 256, 0, stream>>>(xeh, xel, KpTh, KpTl, XkH, XkL, 16384, 4096, 1024);
  ed_transpose_split_v9<<<dim3(32, 64), 256, 0, stream>>>(W_c, WcTh, WcTl, 2048, 1024, 2048, 0, 0);
  ed_enc_v9<<<256, 1024, 87040, stream>>>(src, RpTh, RpTl, XkH, XkL, enc_b,
                                          hpkE0, hpkE1, cbuf, hsf, barsE);
  ed_cvt_v9<<<1024, 256, 0, stream>>>(W_a, WaB, 1048576);
  ed_transpose_v9<<<dim3(1000, 32), 256, 0, stream>>>(W_out, WoTh, 1024, 32000, 1024, 0, 0);
  ed_transpose_split_v9<<<dim3(128, 32), 256, 0, stream>>>(dec_K, KRTh, KRTl, 1024, 4096, 2048, 0, 1);
  ed_transpose_split_v9<<<dim3(128, 32), 256, 0, stream>>>(dec_R, KRTh, KRTl, 1024, 4096, 2048, 1024, 1);
  ed_dec_v9<<<256, 1024, 150528, stream>>>(src, KRTh, KRTl, dec_b, WcTh, WcTl, b_c,
                                           WoTh, b_out, W_out, dec_emb, WaB, qbuf, hsf,
                                           hpkE0, hpkD0, cbuf, pctx, psum, ahpk, ahb32,
                                           rsum, rmaxp, ridxp, ybuf, (float*)d_out,
                                           barsG, barsL);
}

// Round 10
// 12105.583 us; speedup vs baseline: 1.1920x; 1.0049x over previous
//
#include <hip/hip_runtime.h>
#include <hip/hip_bf16.h>

typedef __hip_bfloat16 bf16;
typedef short bf8v __attribute__((ext_vector_type(8)));   // 8 x bf16 (4 VGPR)
typedef float f32x4 __attribute__((ext_vector_type(4)));

#define DEVINL __device__ __forceinline__
#define MFMA16(a, b, c) __builtin_amdgcn_mfma_f32_16x16x32_bf16((a), (b), (c), 0, 0, 0)

DEVINL float us2f(unsigned short u) { unsigned v = ((unsigned)u) << 16; return __uint_as_float(v); }
DEVINL float b2f(bf16 x) { return __bfloat162float(x); }
DEVINL bf16 f2b(float x) { return __float2bfloat16(x); }
DEVINL float sigf(float x) { return 1.0f / (1.0f + expf(-x)); }
DEVINL unsigned short f2bu(float f) { bf16 h = __float2bfloat16(f); return *(unsigned short*)&h; }

DEVINL void gload16(const void* g, void* l) {
  __builtin_amdgcn_global_load_lds((const __attribute__((address_space(1))) void*)g,
                                   (__attribute__((address_space(3))) void*)l, 16, 0, 0);
}

// ---- relaxed agent-scope atomics ----
DEVINL unsigned ald(const unsigned* p) {
  return __hip_atomic_load(p, __ATOMIC_RELAXED, __HIP_MEMORY_SCOPE_AGENT);
}
DEVINL void ast(unsigned* p, unsigned v) {
  __hip_atomic_store(p, v, __ATOMIC_RELAXED, __HIP_MEMORY_SCOPE_AGENT);
}
DEVINL float aldf(const float* p) { unsigned u = ald((const unsigned*)p); return __uint_as_float(u); }
DEVINL void astf(float* p, float v) { ast((unsigned*)p, __float_as_uint(v)); }

// ---- remap: cgl determines XCD so the 4 bg-copies of a cgl share one L2 ----
// g = bid&7 (XCD), s = bid>>3: cgl = g*8 + (s&7), bg = s>>3.
DEVINL int remap_lid(int bid) {
  int g = bid & 7, s = bid >> 3;
  return (s >> 3) * 64 + g * 8 + (s & 7);
}

// ---- global 256-block barrier (8 XCD-local groups x 32), parity-buffered ----
DEVINL void gridbar2(unsigned* bars, unsigned lgen) {
  __syncthreads();
  if (threadIdx.x == 0) {
    unsigned s = lgen & 1;
    unsigned g = blockIdx.x & 7;
    unsigned* grp = bars + (g * 2 + s) * 16;
    unsigned* top = bars + (16 + s) * 16;
    unsigned* gen = bars + 288;
    unsigned t = __hip_atomic_fetch_add(grp, 1u, __ATOMIC_RELAXED, __HIP_MEMORY_SCOPE_AGENT);
    if (t == 31u) {
      ast(grp, 0u);
      unsigned tt = __hip_atomic_fetch_add(top, 1u, __ATOMIC_RELAXED, __HIP_MEMORY_SCOPE_AGENT);
      if (tt == 7u) {
        ast(top, 0u);
        asm volatile("s_waitcnt vmcnt(0)");
        ast(gen, lgen + 1u);
      }
    }
    while (ald(gen) <= lgen) __builtin_amdgcn_s_sleep(2);
  }
  __syncthreads();
}

// ---- local 64-block barrier (2 groups x 32) ----
DEVINL void bar64(unsigned* b, unsigned lgen, int lid) {
  __syncthreads();
  if (threadIdx.x == 0) {
    unsigned s = lgen & 1;
    unsigned* grp = b + (((unsigned)(lid >> 5) & 1u) * 2 + s) * 16;
    unsigned* top = b + (4 + s) * 16;
    unsigned* gen = b + 96;
    unsigned t = __hip_atomic_fetch_add(grp, 1u, __ATOMIC_RELAXED, __HIP_MEMORY_SCOPE_AGENT);
    if (t == 31u) {
      ast(grp, 0u);
      unsigned tt = __hip_atomic_fetch_add(top, 1u, __ATOMIC_RELAXED, __HIP_MEMORY_SCOPE_AGENT);
      if (tt == 1u) {
        ast(top, 0u);
        asm volatile("s_waitcnt vmcnt(0)");
        ast(gen, lgen + 1u);
      }
    }
    while (ald(gen) <= lgen) __builtin_amdgcn_s_sleep(1);
  }
  __syncthreads();
}

// ---------------- ws layout (bytes); total <= 272,629,760 ----
#define OKPT_H  ((size_t)0)
#define OKPT_L  ((size_t)8388608)
#define ORPT_H  ((size_t)16777216)
#define ORPT_L  ((size_t)25165824)
#define OXE_H   ((size_t)35651584)
#define OXE_L   ((size_t)69206016)
#define OHSF5   ((size_t)35651584)
#define XCH     ((size_t)136314880)
#define OHPK_E0 (XCH + 0)
#define OHPK_E1 (XCH + 262144)
#define OHPK_D0 (XCH + 524288)
#define OCBUF5  (XCH + 1048576)
#define OAHPK   (XCH + 1310720)
#define ORSUM5  (XCH + 1572864)
#define ORMAX5  (XCH + 1638400)
#define ORIDX5  (XCH + 1769472)
#define OPSUM5  (XCH + 1900544)
#define OBARS5  (XCH + 1901568)
#define OYBUF   (XCH + 1917952)
#define OAHB    (XCH + 1933312)
#define OXK_L5  ((size_t)138412032)
#define OWCT_H  ((size_t)0)
#define OWCT_L  ((size_t)4194304)
#define OPCTX5  ((size_t)8388608)
#define OQBUF   ORPT_H
#define OWAB    (ORPT_H + 262144)
#define OWOT5   ((size_t)138412032)
#define OKRTH5  ((size_t)203948032)
#define OKRTL5  ((size_t)220725248)

#define DELTA   1e-4f

// decoder LDS pool offsets (pool 150528)
#define D_LH   0
#define D_LL   32768
#define D_ZS   65536
#define D_KB   83968      /* double-buffered: +(c&1)*32768; hi at +0, lo at +16384 */
#define D4_A   0          /* double: +(c&1)*16384 */
#define D4_W   32768      /* double: +(c&1)*32768 -> ends 98304 */
#define D4_E   98304      /* [64][129] f32 -> ends 131328 */
#define D_WA   0
#define D_ES   65536
#define D_ZS3  0
#define D_PSC2 0
#define D_RV   8192
#define D_RR   10240
#define D_CCN  12288
#define D_CAND 12352
#define D_RS   12480
#define D_RC   12608
#define D_YL   149504
#define D_INV  149568
#define D_RT   149632

// ---------------- utility kernels ----------------
__global__ void ed_zero_vA(float4* p, int n) {
  int i = blockIdx.x * 256 + threadIdx.x;
  if (i < n) p[i] = make_float4(0.f, 0.f, 0.f, 0.f);
}

__global__ void ed_cvt_vA(const float* __restrict__ in, bf16* __restrict__ out, int n) {
  int i = (blockIdx.x * 256 + threadIdx.x) * 4;
  if (i + 3 < n) {
    float4 v = *(const float4*)(in + i);
    ushort4 o;
    o.x = f2bu(v.x); o.y = f2bu(v.y); o.z = f2bu(v.z); o.w = f2bu(v.w);
    *(ushort4*)(out + i) = o;
  }
}

__global__ void ed_transpose_vA(const float* __restrict__ in, bf16* __restrict__ out,
                                int R, int C, int ostride, int ooff, int perm) {
  __shared__ float tile[32][33];
  int c0 = blockIdx.x * 32, r0 = blockIdx.y * 32;
  int tx = threadIdx.x & 31, ty0 = threadIdx.x >> 5;
#pragma unroll
  for (int i = 0; i < 4; i++) {
    int ty = ty0 + i * 8;
    tile[ty][tx] = in[(size_t)(r0 + ty) * C + c0 + tx];
  }
  __syncthreads();
#pragma unroll
  for (int i = 0; i < 4; i++) {
    int ty = ty0 + i * 8;
    int c = c0 + ty;
    int oc = perm ? ((c & 1023) * 4 + (c >> 10)) : c;
    out[(size_t)oc * ostride + ooff + r0 + tx] = f2b(tile[tx][ty]);
  }
}

__global__ void ed_transpose_split_vA(const float* __restrict__ in, bf16* __restrict__ oh,
                                      bf16* __restrict__ ol, int R, int C, int ostride,
                                      int ooff, int perm) {
  __shared__ float tile[32][33];
  int c0 = blockIdx.x * 32, r0 = blockIdx.y * 32;
  int tx = threadIdx.x & 31, ty0 = threadIdx.x >> 5;
#pragma unroll
  for (int i = 0; i < 4; i++) {
    int ty = ty0 + i * 8;
    tile[ty][tx] = in[(size_t)(r0 + ty) * C + c0 + tx];
  }
  __syncthreads();
#pragma unroll
  for (int i = 0; i < 4; i++) {
    int ty = ty0 + i * 8;
    int c = c0 + ty;
    int oc = perm ? ((c & 1023) * 4 + (c >> 10)) : c;
    float v = tile[tx][ty];
    bf16 hh = f2b(v);
    size_t o = (size_t)oc * ostride + ooff + r0 + tx;
    oh[o] = hh;
    ol[o] = f2b(v - b2f(hh));
  }
}

__global__ void ed_gather_split_vA(const int* __restrict__ src, const float* __restrict__ emb,
                                   bf16* __restrict__ xh, bf16* __restrict__ xl) {
  int bid = blockIdx.x;
  int t = bid >> 6, b = bid & 63;
  int tok = src[b * 256 + t];
  const float* rowp = emb + (size_t)tok * 1024;
  int i = threadIdx.x * 4;
  float4 v = *(const float4*)(rowp + i);
  bf16 h0 = f2b(v.x), h1 = f2b(v.y), h2 = f2b(v.z), h3 = f2b(v.w);
  ushort4 oh, ol;
  oh.x = *(unsigned short*)&h0; oh.y = *(unsigned short*)&h1;
  oh.z = *(unsigned short*)&h2; oh.w = *(unsigned short*)&h3;
  ol.x = f2bu(v.x - b2f(h0)); ol.y = f2bu(v.y - b2f(h1));
  ol.z = f2bu(v.z - b2f(h2)); ol.w = f2bu(v.w - b2f(h3));
  *(ushort4*)(xh + (size_t)bid * 1024 + i) = oh;
  *(ushort4*)(xl + (size_t)bid * 1024 + i) = ol;
}

// ---------------- split-precision GEMM (3-term), split output (Xk) ----------------
__global__ __launch_bounds__(256, 2) void ed_gemm3_vA(
    const bf16* __restrict__ Ah, const bf16* __restrict__ Al,
    const bf16* __restrict__ Bh, const bf16* __restrict__ Bl,
    bf16* __restrict__ Ch, bf16* __restrict__ Cl, int M, int N, int K) {
  __shared__ __align__(16) bf16 Ash[128 * 32];
  __shared__ __align__(16) bf16 Asl[128 * 32];
  __shared__ __align__(16) bf16 Bsh[128 * 32];
  __shared__ __align__(16) bf16 Bsl[128 * 32];
  int m0 = blockIdx.y * 128, n0 = blockIdx.x * 128;
  int tid = threadIdx.x, w = tid >> 6, l = tid & 63;
  int wm = w >> 1, wn = w & 1;
  int lr = l & 15, lq = l >> 4;
  f32x4 acc[4][4] = {};
  for (int k0 = 0; k0 < K; k0 += 32) {
    __syncthreads();
#pragma unroll
    for (int j = 0; j < 2; j++) {
      int o = (w * 2 + j) * 1024 + l * 16;
      int rrow = o >> 6, kk = (o & 63) >> 1;
      gload16(Ah + (size_t)(m0 + rrow) * K + k0 + kk, (char*)Ash + (w * 2 + j) * 1024);
      gload16(Al + (size_t)(m0 + rrow) * K + k0 + kk, (char*)Asl + (w * 2 + j) * 1024);
      gload16(Bh + (size_t)(n0 + rrow) * K + k0 + kk, (char*)Bsh + (w * 2 + j) * 1024);
      gload16(Bl + (size_t)(n0 + rrow) * K + k0 + kk, (char*)Bsl + (w * 2 + j) * 1024);
    }
    __syncthreads();
#pragma unroll
    for (int mi = 0; mi < 4; mi++) {
      bf8v a_h = *(const bf8v*)(Ash + (wm * 64 + mi * 16 + lr) * 32 + lq * 8);
      bf8v a_l = *(const bf8v*)(Asl + (wm * 64 + mi * 16 + lr) * 32 + lq * 8);
#pragma unroll
      for (int ni = 0; ni < 4; ni++) {
        bf8v b_h = *(const bf8v*)(Bsh + (wn * 64 + ni * 16 + lr) * 32 + lq * 8);
        bf8v b_l = *(const bf8v*)(Bsl + (wn * 64 + ni * 16 + lr) * 32 + lq * 8);
        acc[mi][ni] = MFMA16(a_h, b_h, acc[mi][ni]);
        acc[mi][ni] = MFMA16(a_h, b_l, acc[mi][ni]);
        acc[mi][ni] = MFMA16(a_l, b_h, acc[mi][ni]);
      }
    }
  }
#pragma unroll
  for (int mi = 0; mi < 4; mi++)
#pragma unroll
    for (int ni = 0; ni < 4; ni++)
#pragma unroll
      for (int r = 0; r < 4; r++) {
        float v = acc[mi][ni][r];
        bf16 hh = f2b(v);
        size_t idx = (size_t)(m0 + wm * 64 + mi * 16 + lq * 4 + r) * N + n0 + wn * 64 + ni * 16 + lr;
        Ch[idx] = hh;
        Cl[idx] = f2b(v - b2f(hh));
      }
}

// ---------------- encoder: cgl-on-XCD remap; per-bg local barriers ----------------
__global__ __launch_bounds__(1024, 4) void ed_enc_vA(
    const int* __restrict__ src, const bf16* __restrict__ Rh, const bf16* __restrict__ Rl,
    const bf16* __restrict__ Xh, const bf16* __restrict__ Xl, const float* __restrict__ enc_b,
    unsigned* hpk0, unsigned* hpk1, float* __restrict__ cbuf,
    float* __restrict__ hsf, unsigned* barsE) {
  extern __shared__ char sm[];
  bf16* lh = (bf16*)sm;
  bf16* ll = (bf16*)(sm + 32768);
  float* zs = (float*)(sm + 65536);
  float* xkf = (float*)(sm + 82944);
  int bid = blockIdx.x, tid = threadIdx.x;
  int lid_all = remap_lid(bid);
  int bg = lid_all >> 6, cg = lid_all & 63, lid = lid_all & 63;
  unsigned* barL = barsE + bg * 128;
  int wv = tid >> 6, l = tid & 63, lr = l & 15, lq = l >> 4;
  int kq = wv >> 2, cs = wv & 3;
  int srow = tid >> 6, sj0 = (tid & 63) * 16;
  int grow = tid >> 4, gul = tid & 15;
  bf8v Rh_[8], Rl_[8];
  {
    const bf16* bh = Rh + (size_t)(cg * 64 + cs * 16 + lr) * 1024 + kq * 256 + lq * 8;
    const bf16* bl = Rl + (size_t)(cg * 64 + cs * 16 + lr) * 1024 + kq * 256 + lq * 8;
#pragma unroll
    for (int i = 0; i < 8; i++) {
      Rh_[i] = *(const bf8v*)(bh + i * 32);
      Rl_[i] = *(const bf8v*)(bl + i * 32);
    }
  }
  float bi[4];
  float c_ = 0.f;
  if (tid < 256) {
#pragma unroll
    for (int g = 0; g < 4; g++) {
      int colp = cg * 64 + gul * 4 + g;
      bi[g] = enc_b[(colp & 3) * 1024 + (colp >> 2)];
    }
  }
  unsigned *hc = hpk0, *hn = hpk1;
  unsigned lgen = 0;
  for (int t = 0; t < 256; t++) {
    {
      const unsigned* hrow = hc + (size_t)(bg * 16 + srow) * 1024 + sj0;
      unsigned u[16];
#pragma unroll
      for (int j = 0; j < 16; j++) u[j] = ald(hrow + j);
      int r8 = (srow & 7) << 3;
#pragma unroll
      for (int j = 0; j < 16; j += 2) {
        int es = (sj0 + j) ^ r8;
        *(unsigned*)((char*)lh + srow * 2048 + es * 2) = (u[j] >> 16) | (u[j + 1] & 0xffff0000u);
        *(unsigned*)((char*)ll + srow * 2048 + es * 2) = (u[j] & 0xffffu) | (u[j + 1] << 16);
      }
    }
    {
      int xr = tid >> 6, xc = tid & 63;
      size_t xi = ((size_t)t * 64 + bg * 16 + xr) * 4096 + cg * 64 + xc;
      unsigned short xh = __builtin_nontemporal_load((const unsigned short*)(Xh + xi));
      unsigned short xl = __builtin_nontemporal_load((const unsigned short*)(Xl + xi));
      xkf[xr * 64 + xc] = us2f(xh) + us2f(xl);
    }
    __syncthreads();
    {
      f32x4 acc = {0.f, 0.f, 0.f, 0.f};
      int r8 = (lr & 7) << 3;
#pragma unroll
      for (int i = 0; i < 8; i++) {
        int e0 = kq * 256 + i * 32 + lq * 8;
        int es = e0 ^ r8;
        bf8v a_h = *(const bf8v*)((char*)lh + lr * 2048 + es * 2);
        bf8v a_l = *(const bf8v*)((char*)ll + lr * 2048 + es * 2);
        acc = MFMA16(a_h, Rh_[i], acc);
        acc = MFMA16(a_h, Rl_[i], acc);
        acc = MFMA16(a_l, Rh_[i], acc);
        acc = MFMA16(a_l, Rl_[i], acc);
      }
#pragma unroll
      for (int r = 0; r < 4; r++) zs[(kq * 16 + lq * 4 + r) * 68 + cs * 16 + lr] = acc[r];
    }
    __syncthreads();
    if (tid < 256) {
      int b_ = bg * 16 + grow, u = cg * 16 + gul;
      float zz[4];
#pragma unroll
      for (int g = 0; g < 4; g++) {
        int cc = gul * 4 + g;
        zz[g] = zs[(0 + grow) * 68 + cc] + zs[(16 + grow) * 68 + cc] +
                zs[(32 + grow) * 68 + cc] + zs[(48 + grow) * 68 + cc] +
                xkf[grow * 64 + cc] + bi[g];
      }
      float iv = sigf(zz[0]), fv = sigf(zz[1]), gv = tanhf(zz[2]), ov = sigf(zz[3]);
      float cn = fv * c_ + iv * gv;
      float hnv = ov * tanhf(cn);
      bool m = src[b_ * 256 + t] > 0;
      int es = u ^ ((grow & 7) << 3);
      float hold = b2f(*(const bf16*)((char*)lh + grow * 2048 + es * 2)) +
                   b2f(*(const bf16*)((char*)ll + grow * 2048 + es * 2));
      float hv = m ? hnv : hold;
      c_ = m ? cn : c_;
      unsigned short uh = f2bu(hv);
      unsigned pkv = ((unsigned)uh << 16) | (unsigned)f2bu(hv - us2f(uh));
      ast(hn + (size_t)b_ * 1024 + u, pkv);
      hsf[((size_t)t * 64 + b_) * 1024 + u] = hv;
    }
    bar64(barL, lgen, lid);
    lgen++;
    unsigned* tp = hc; hc = hn; hn = tp;
  }
  if (tid < 256) cbuf[(size_t)(bg * 16 + grow) * 1024 + cg * 16 + gul] = c_;
}

// ---------------- decoder LSTM (pipelined KRT staging, counted vmcnt) ----------------
DEVINL void dec_lstmA(int bg, int cgl, int tid, char* sm,
                      const unsigned* hc, unsigned* hn,
                      const float* __restrict__ dec_emb,
                      const bf16* __restrict__ Kh, const bf16* __restrict__ Kl,
                      const float* __restrict__ dec_b, float& c_) {
  bf16* lh = (bf16*)(sm + D_LH);
  bf16* ll = (bf16*)(sm + D_LL);
  int wv = tid >> 6, l = tid & 63, lr = l & 15, lq = l >> 4;
  int kg2 = wv >> 2, cs = wv & 3;
  const int* y_l = (const int*)(sm + D_YL);
  float* zs = (float*)(sm + D_ZS);
  // stage h -> swizzled LDS
  {
    int srow = tid >> 6, sl = tid & 63;
    const unsigned* hrow = hc + (size_t)(bg * 16 + srow) * 1024 + sl * 16;
    unsigned u[16];
#pragma unroll
    for (int j = 0; j < 16; j++) u[j] = ald(hrow + j);
    uint4 ha, hb, la, lb;
    ha.x = (u[0] >> 16) | (u[1] & 0xffff0000u);  ha.y = (u[2] >> 16) | (u[3] & 0xffff0000u);
    ha.z = (u[4] >> 16) | (u[5] & 0xffff0000u);  ha.w = (u[6] >> 16) | (u[7] & 0xffff0000u);
    hb.x = (u[8] >> 16) | (u[9] & 0xffff0000u);  hb.y = (u[10] >> 16) | (u[11] & 0xffff0000u);
    hb.z = (u[12] >> 16) | (u[13] & 0xffff0000u); hb.w = (u[14] >> 16) | (u[15] & 0xffff0000u);
    la.x = (u[0] & 0xffffu) | (u[1] << 16);  la.y = (u[2] & 0xffffu) | (u[3] << 16);
    la.z = (u[4] & 0xffffu) | (u[5] << 16);  la.w = (u[6] & 0xffffu) | (u[7] << 16);
    lb.x = (u[8] & 0xffffu) | (u[9] << 16);  lb.y = (u[10] & 0xffffu) | (u[11] << 16);
    lb.z = (u[12] & 0xffffu) | (u[13] << 16); lb.w = (u[14] & 0xffffu) | (u[15] << 16);
    int swz = (srow & 7) << 4;
    char* rbh = (char*)lh + srow * 2048;
    char* rbl = (char*)ll + srow * 2048;
    *(uint4*)(rbh + ((sl * 32) ^ swz)) = ha;
    *(uint4*)(rbh + ((sl * 32 + 16) ^ swz)) = hb;
    *(uint4*)(rbl + ((sl * 32) ^ swz)) = la;
    *(uint4*)(rbl + ((sl * 32 + 16) ^ swz)) = lb;
  }
  // preload x = dec_emb row fragments into registers (chunks 0..7)
  bf8v xah[8], xal[8];
  {
    const float* xr = dec_emb + (size_t)y_l[lr] * 1024 + kg2 * 32 + lq * 8;
#pragma unroll
    for (int c = 0; c < 8; c++) {
      float4 v0 = *(const float4*)(xr + c * 128);
      float4 v1 = *(const float4*)(xr + c * 128 + 4);
      float vs[8] = {v0.x, v0.y, v0.z, v0.w, v1.x, v1.y, v1.z, v1.w};
#pragma unroll
      for (int e = 0; e < 8; e++) {
        unsigned short uh = f2bu(vs[e]);
        xah[c][e] = (short)uh;
        xal[c][e] = (short)f2bu(vs[e] - us2f(uh));
      }
    }
  }
  auto issueKB = [&](int c) {
    int i = wv * 64 + l;
    int col = i >> 4, j = i & 15;
    size_t se = (size_t)(cgl * 64 + col) * 2048 + c * 128 + ((size_t)(j ^ (col & 7)) << 3);
    char* dst = (char*)sm + D_KB + (c & 1) * 32768 + wv * 1024;
    gload16(Kh + se, dst);
    gload16(Kl + se, dst + 16384);
  };
  issueKB(0);
  issueKB(1);
  __syncthreads();  // h+x staged; kb0/kb1 drained
  f32x4 acc = {0.f, 0.f, 0.f, 0.f};
  int colB = cs * 16 + lr;
  int bswz = (colB & 7) << 4;
  int aswz = (lr & 7) << 4;
#pragma unroll
  for (int c = 0; c < 16; c++) {
    if (c < 15) asm volatile("s_waitcnt vmcnt(2)" ::: "memory");
    else        asm volatile("s_waitcnt vmcnt(0)" ::: "memory");
    __builtin_amdgcn_s_barrier();
    __builtin_amdgcn_sched_barrier(0);
    {
      int kl = kg2 * 32 + lq * 8;
      const char* kb = (const char*)sm + D_KB + (c & 1) * 32768;
      bf8v b_h = *(const bf8v*)(kb + colB * 256 + ((kl * 2) ^ bswz));
      bf8v b_l = *(const bf8v*)(kb + 16384 + colB * 256 + ((kl * 2) ^ bswz));
      bf8v a_h, a_l;
      if (c < 8) {
        a_h = xah[c];
        a_l = xal[c];
      } else {
        int hk = (c - 8) * 128 + kl;
        a_h = *(const bf8v*)((char*)lh + lr * 2048 + ((hk * 2) ^ aswz));
        a_l = *(const bf8v*)((char*)ll + lr * 2048 + ((hk * 2) ^ aswz));
      }
      acc = MFMA16(a_h, b_h, acc);
      acc = MFMA16(a_h, b_l, acc);
      acc = MFMA16(a_l, b_h, acc);
      acc = MFMA16(a_l, b_l, acc);
    }
    __builtin_amdgcn_sched_barrier(0);
    __builtin_amdgcn_s_barrier();
    __builtin_amdgcn_sched_barrier(0);
    if (c + 2 < 16) issueKB(c + 2);
  }
#pragma unroll
  for (int r = 0; r < 4; r++) zs[(kg2 * 16 + lq * 4 + r) * 68 + cs * 16 + lr] = acc[r];
  __syncthreads();
  if (tid < 256) {
    int grow = tid >> 4, gul = tid & 15;
    int b_ = bg * 16 + grow;
    float zz[4];
#pragma unroll
    for (int g = 0; g < 4; g++) {
      int cc = gul * 4 + g;
      int colp = cgl * 64 + cc;
      float v = zs[(0 + grow) * 68 + cc] + zs[(16 + grow) * 68 + cc] +
                zs[(32 + grow) * 68 + cc] + zs[(48 + grow) * 68 + cc];
      zz[g] = v + dec_b[(colp & 3) * 1024 + (colp >> 2)];
    }
    float iv = sigf(zz[0]), fv = sigf(zz[1]), gv = tanhf(zz[2]), ov = sigf(zz[3]);
    float cn = fv * c_ + iv * gv;
    c_ = cn;
    float hv = ov * tanhf(cn);
    unsigned short uh = f2bu(hv);
    unsigned pkv = ((unsigned)uh << 16) | (unsigned)f2bu(hv - us2f(uh));
    ast(hn + (size_t)b_ * 1024 + cgl * 16 + gul, pkv);
  }
}

// ---------------- decoder persistent kernel ----------------
__global__ __launch_bounds__(1024, 4) void ed_dec_vA(
    const int* __restrict__ src,
    const bf16* __restrict__ KRh, const bf16* __restrict__ KRl, const float* __restrict__ dec_b,
    const bf16* __restrict__ WcTh, const bf16* __restrict__ WcTl, const float* __restrict__ b_cp,
    const bf16* __restrict__ WoTh, const float* __restrict__ b_op,
    const float* __restrict__ Wout_f32, const float* __restrict__ dec_emb,
    const bf16* __restrict__ WaB, float* __restrict__ qbuf,
    const float* __restrict__ hsf,
    unsigned* hpkA, unsigned* hpkB, float* __restrict__ cbuf,
    float* __restrict__ pctx, float* __restrict__ psum, unsigned* ahpk, unsigned* ahb32,
    float* __restrict__ rowsum, float* __restrict__ rmax, int* __restrict__ ridx,
    unsigned* ybuf, float* __restrict__ out, unsigned* barsG, unsigned* barsL) {
  extern __shared__ char sm[];
  int bid = blockIdx.x, tid = threadIdx.x;
  int lid_all = remap_lid(bid);
  int bg = lid_all >> 6, cgl = lid_all & 63, lid = lid_all & 63;
  unsigned* barL = barsL + bg * 128;
  int wv = tid >> 6, l = tid & 63, lr = l & 15, lq = l >> 4;
  float c_ = 0.f;
  if (tid < 256) c_ = cbuf[(size_t)(bg * 16 + (tid >> 4)) * 1024 + cgl * 16 + (tid & 15)];
  unsigned *hc = hpkA, *hn = hpkB;
  unsigned lgenL = 0, lgenG = 0;

  if (tid < 16) ((int*)(sm + D_YL))[tid] = 1;
  __syncthreads();
  dec_lstmA(bg, cgl, tid, sm, hc, hn, dec_emb, KRh, KRl, dec_b, c_);
  bar64(barL, lgenL, lid); lgenL++;
  { unsigned* tp = hc; hc = hn; hn = tp; }

  int p4base = lid_all * 125;
  auto issueW4 = [&](int c) {
#pragma unroll
    for (int r = 0; r < 2; r++) {
      int i = wv * 128 + r * 64 + l;
      int col = i >> 4, j = i & 15;
      int ccol = col < 125 ? col : 124;
      size_t se = (size_t)(p4base + ccol) * 1024 + c * 128 + ((size_t)(j ^ (col & 7)) << 3);
      gload16(WoTh + se, (char*)sm + D4_W + (c & 1) * 32768 + wv * 2048 + r * 1024);
    }
  };
  auto stageA4 = [&](int ca) {
    int row = tid >> 4, l16 = tid & 15;
    const unsigned* ap = ahb32 + (size_t)row * 512 + ca * 64 + l16 * 4;
    uint4 hv;
    hv.x = ald(ap); hv.y = ald(ap + 1); hv.z = ald(ap + 2); hv.w = ald(ap + 3);
    *(uint4*)((char*)sm + D4_A + (ca & 1) * 16384 + row * 256 + ((l16 ^ (row & 7)) << 4)) = hv;
  };

  for (int st = 0; st < 32; st++) {
    // ---- PQ: q[b] = W_a @ h[b] (bf16 W_a); active blocks cgl<16 ----
    if (cgl < 16) {
      int colb = cgl * 64;
      int kq = wv >> 2, nq = wv & 3;
      float* zs = (float*)(sm + D_ZS);
      f32x4 acc = {0.f, 0.f, 0.f, 0.f};
      const unsigned* hrow = hc + (size_t)(bg * 16 + lr) * 1024;
      const bf16* warow = WaB + (size_t)(colb + nq * 16 + lr) * 1024;
#pragma unroll
      for (int i = 0; i < 8; i++) {
        int k = kq * 256 + i * 32 + lq * 8;
        bf8v a;
        const unsigned* hp = hrow + k;
#pragma unroll
        for (int e = 0; e < 8; e++) a[e] = (short)(ald(hp + e) >> 16);
        bf8v b = *(const bf8v*)(warow + k);
        acc = MFMA16(a, b, acc);
      }
#pragma unroll
      for (int r = 0; r < 4; r++) zs[(kq * 16 + lq * 4 + r) * 68 + nq * 16 + lr] = acc[r];
      __syncthreads();
      {
        int mrow = tid >> 6, col = tid & 63;
        float v = zs[(0 + mrow) * 68 + col] + zs[(16 + mrow) * 68 + col] +
                  zs[(32 + mrow) * 68 + col] + zs[(48 + mrow) * 68 + col];
        astf(qbuf + (size_t)(bg * 16 + mrow) * 1024 + colb + col, v);
      }
    }
    bar64(barL, lgenL, lid); lgenL++;
    // ---- P1: fused scores+ctx, single pass over hsf; block = (b, kg) ----
    {
      int b_ = lid_all >> 2, kg = lid_all & 3;
      float* wacc = (float*)(sm + D_WA);
      float* es = (float*)(sm + D_ES);
      float qr[16];
      {
        const float* qb = qbuf + (size_t)b_ * 1024 + l * 16;
        *(float4*)&qr[0]  = *(const float4*)(qb);
        *(float4*)&qr[4]  = *(const float4*)(qb + 4);
        *(float4*)&qr[8]  = *(const float4*)(qb + 8);
        *(float4*)&qr[12] = *(const float4*)(qb + 12);
      }
      float a16[16];
#pragma unroll
      for (int j = 0; j < 16; j++) a16[j] = 0.f;
      float esum = 0.f;
#pragma unroll
      for (int i = 0; i < 4; i++) {
        int kglob = kg * 64 + wv * 4 + i;
        const float* hrow = hsf + ((size_t)kglob * 64 + b_) * 1024 + l * 16;
        float4 v0 = *(const float4*)hrow;
        float4 v1 = *(const float4*)(hrow + 4);
        float4 v2 = *(const float4*)(hrow + 8);
        float4 v3 = *(const float4*)(hrow + 12);
        float vv[16] = {v0.x, v0.y, v0.z, v0.w, v1.x, v1.y, v1.z, v1.w,
                        v2.x, v2.y, v2.z, v2.w, v3.x, v3.y, v3.z, v3.w};
        float p = 0.f;
#pragma unroll
        for (int j = 0; j < 16; j++) p += qr[j] * vv[j];
#pragma unroll
        for (int off = 32; off > 0; off >>= 1) p += __shfl_xor(p, off);
        float e = (src[b_ * 256 + kglob] > 0) ? expf(p) : 0.f;
        esum += e;
#pragma unroll
        for (int j = 0; j < 16; j++) a16[j] += e * vv[j];
      }
#pragma unroll
      for (int j = 0; j < 16; j++) wacc[wv * 1024 + j * 64 + l] = a16[j];
      if (l == 0) es[wv] = esum;
      __syncthreads();
      {
        float v = 0.f;
#pragma unroll
        for (int w2 = 0; w2 < 16; w2++) v += wacc[w2 * 1024 + tid];
        int logical = (tid & 63) * 16 + (tid >> 6);
        astf(pctx + ((size_t)kg * 64 + b_) * 1024 + logical, v);
      }
      if (tid == 0) {
        float s_ = 0.f;
#pragma unroll
        for (int w2 = 0; w2 < 16; w2++) s_ += es[w2];
        astf(psum + kg * 64 + b_, s_);
      }
    }
    bar64(barL, lgenL, lid); lgenL++;
    // ---- P3: ctx-reduce + ah = tanh([ctx,h]@W_c + b_c); block = (bg, 16-col) ----
    {
      float* inv_l = (float*)(sm + D_INV);
      if (tid < 16) {
        int rb = bg * 16 + tid;
        float sg = aldf(psum + rb) + aldf(psum + 64 + rb) +
                   aldf(psum + 128 + rb) + aldf(psum + 192 + rb);
        inv_l[tid] = 1.0f / sg;
      }
      __syncthreads();
      float* zs3 = (float*)(sm + D_ZS3);
      {
        int kq = wv;
        f32x4 acc = {0.f, 0.f, 0.f, 0.f};
        const bf16* bh = WcTh + (size_t)(cgl * 16 + lr) * 2048;
        const bf16* bl = WcTl + (size_t)(cgl * 16 + lr) * 2048;
        float inv = inv_l[lr];
#pragma unroll
        for (int i = 0; i < 4; i++) {
          int k = kq * 128 + i * 32 + lq * 8;
          bf8v a_h, a_l;
          if (k < 1024) {
            const float* p0 = pctx + (size_t)(bg * 16 + lr) * 1024 + k;
#pragma unroll
            for (int e = 0; e < 8; e++) {
              float v = (aldf(p0 + e) + aldf(p0 + 65536 + e) +
                         aldf(p0 + 131072 + e) + aldf(p0 + 196608 + e)) * inv;
              unsigned short uh = f2bu(v);
              a_h[e] = (short)uh;
              a_l[e] = (short)f2bu(v - us2f(uh));
            }
          } else {
            const unsigned* hp = hc + (size_t)(bg * 16 + lr) * 1024 + (k - 1024);
#pragma unroll
            for (int e = 0; e < 8; e++) {
              unsigned u = ald(hp + e);
              a_h[e] = (short)(u >> 16);
              a_l[e] = (short)(u & 0xffffu);
            }
          }
          bf8v b_h = *(const bf8v*)(bh + k);
          bf8v b_l = *(const bf8v*)(bl + k);
          acc = MFMA16(a_h, b_h, acc); acc = MFMA16(a_h, b_l, acc);
          acc = MFMA16(a_l, b_h, acc); acc = MFMA16(a_l, b_l, acc);
        }
#pragma unroll
        for (int r = 0; r < 4; r++) zs3[(kq * 16 + lq * 4 + r) * 17 + lr] = acc[r];
      }
      __syncthreads();
      if (tid < 256) {
        int grow = tid >> 4, gcol = tid & 15;
        float v = 0.f;
#pragma unroll
        for (int q = 0; q < 16; q++) v += zs3[(q * 16 + grow) * 17 + gcol];
        v += b_cp[cgl * 16 + gcol];
        float ahv = tanhf(v);
        unsigned short uh = f2bu(ahv);
        unsigned pkv = ((unsigned)uh << 16) | (unsigned)f2bu(ahv - us2f(uh));
        ast(ahpk + (size_t)(bg * 16 + grow) * 1024 + cgl * 16 + gcol, pkv);
        float ahn = __shfl_down(ahv, 1);
        if ((tid & 1) == 0) {
          unsigned pk2 = (unsigned)f2bu(ahv) | ((unsigned)f2bu(ahn) << 16);
          ast(ahb32 + (size_t)(bg * 16 + grow) * 512 + cgl * 8 + (gcol >> 1), pk2);
        }
      }
    }
    // prefetch W chunks 0,1 into LDS; they drain during the global barrier
    issueW4(0);
    issueW4(1);
    gridbar2(barsG, lgenG); lgenG++;
    // ---- P4: pipelined logits (W dbuf + A dbuf, counted vmcnt) ----
    {
      stageA4(0);
      __syncthreads();
      int rg = wv >> 2, cpair = wv & 3;
      f32x4 acc0 = {0.f, 0.f, 0.f, 0.f}, acc1 = {0.f, 0.f, 0.f, 0.f};
#pragma unroll
      for (int c = 0; c < 8; c++) {
        if (c < 7) asm volatile("s_waitcnt vmcnt(2)" ::: "memory");
        else       asm volatile("s_waitcnt vmcnt(0)" ::: "memory");
        __builtin_amdgcn_s_barrier();
        __builtin_amdgcn_sched_barrier(0);
        {
          const char* wb = (const char*)sm + D4_W + (c & 1) * 32768;
          const char* ab = (const char*)sm + D4_A + (c & 1) * 16384;
          int ar = rg * 16 + lr;
          int c0 = cpair * 32 + lr, c1 = c0 + 16;
#pragma unroll
          for (int s = 0; s < 4; s++) {
            int kl = s * 32 + lq * 8;
            bf8v a = *(const bf8v*)(ab + ar * 256 + (((s * 4 + lq) ^ (ar & 7)) << 4));
            bf8v b0 = *(const bf8v*)(wb + c0 * 256 + ((kl * 2) ^ ((c0 & 7) << 4)));
            bf8v b1 = *(const bf8v*)(wb + c1 * 256 + ((kl * 2) ^ ((c1 & 7) << 4)));
            acc0 = MFMA16(a, b0, acc0);
            acc1 = MFMA16(a, b1, acc1);
          }
        }
        if (c < 7) stageA4(c + 1);
        asm volatile("s_waitcnt lgkmcnt(0)" ::: "memory");
        __builtin_amdgcn_sched_barrier(0);
        __builtin_amdgcn_s_barrier();
        __builtin_amdgcn_sched_barrier(0);
        if (c + 2 < 8) issueW4(c + 2);
      }
      __syncthreads();
      float* e = (float*)(sm + D4_E);
      {
        int cl0 = cpair * 32 + lr;
        if (cl0 < 125) {
#pragma unroll
          for (int r = 0; r < 4; r++)
            e[(rg * 16 + lq * 4 + r) * 129 + cl0] = acc0[r] + b_op[p4base + cl0];
        }
        int cl1 = cpair * 32 + 16 + lr;
        if (cl1 < 125) {
#pragma unroll
          for (int r = 0; r < 4; r++)
            e[(rg * 16 + lq * 4 + r) * 129 + cl1] = acc1[r] + b_op[p4base + cl1];
        }
      }
      __syncthreads();
      if (tid < 64) {
        float sm_ = 0.f, v1 = -1e30f, v2 = -1e30f;
        int i1 = 0, i2 = 0;
        for (int c2 = 0; c2 < 125; c2++) {
          float v = e[tid * 129 + c2];
          sm_ += expf(v);
          if (v > v1) { v2 = v1; i2 = i1; v1 = v; i1 = p4base + c2; }
          else if (v > v2) { v2 = v; i2 = p4base + c2; }
        }
        astf(rowsum + lid_all * 64 + tid, sm_);
        astf(rmax + (lid_all * 64 + tid) * 2 + 0, v1);
        ast((unsigned*)ridx + (lid_all * 64 + tid) * 2 + 0, (unsigned)i1);
        astf(rmax + (lid_all * 64 + tid) * 2 + 1, v2);
        ast((unsigned*)ridx + (lid_all * 64 + tid) * 2 + 1, (unsigned)i2);
      }
    }
    gridbar2(barsG, lgenG); lgenG++;
    // ---- P5: probs write (NT) + dedup'd candidate refine (f64) + next LSTM ----
    {
      float* psc2 = (float*)(sm + D_PSC2);
      {
        int rr = tid & 63, pp = tid >> 6;
        float s_ = 0.f;
#pragma unroll 4
        for (int cu = pp * 16; cu < pp * 16 + 16; cu++) s_ += aldf(rowsum + cu * 64 + rr);
        psc2[rr * 17 + pp] = s_;
      }
      __syncthreads();
      float* rt = (float*)(sm + D_RT);
      if (tid < 64) {
        float s_ = 0.f;
#pragma unroll
        for (int p2 = 0; p2 < 16; p2++) s_ += psc2[tid * 17 + p2];
        rt[tid] = s_;
      }
      __syncthreads();
      float* e = (float*)(sm + D4_E);
      {
        for (int i = tid; i < 8000; i += 1024) {
          int r_ = i / 125, c2 = i - r_ * 125;
          float pv = expf(e[r_ * 129 + c2]) / rt[r_];
          __builtin_nontemporal_store(pv, out + ((size_t)r_ * 32 + st) * 32000 + p4base + c2);
        }
      }
      if (st < 31) {
        int* y_l = (int*)(sm + D_YL);
        if (cgl < 16) {
          int rowg = bg * 16 + cgl;
          float* rv = (float*)(sm + D_RV);
          float* rr2 = (float*)(sm + D_RR);
          int* ccnt = (int*)(sm + D_CCN);
          int* cand = (int*)(sm + D_CAND);
          double* rs = (double*)(sm + D_RS);
          int* rc = (int*)(sm + D_RC);
          float myv = -1e30f;
          if (tid < 512) {
            myv = aldf(rmax + ((size_t)(tid >> 1) * 64 + rowg) * 2 + (tid & 1));
            rv[tid] = myv;
            rr2[tid] = myv;
          }
          if (tid == 0) ccnt[0] = 0;
          __syncthreads();
          for (int w2 = 256; w2 >= 1; w2 >>= 1) {
            if (tid < w2) rr2[tid] = fmaxf(rr2[tid], rr2[tid + w2]);
            __syncthreads();
          }
          float thr = rr2[0] - DELTA;
          if (tid < 512 && myv >= thr) {
            int slot = atomicAdd(&ccnt[0], 1);
            if (slot < 16)
              cand[slot] = (int)ald((const unsigned*)ridx +
                                    ((size_t)(tid >> 1) * 64 + rowg) * 2 + (tid & 1));
          }
          __syncthreads();
          int cnt = ccnt[0] < 16 ? ccnt[0] : 16;
          if (wv < cnt) {
            int c = cand[wv];
            double s_ = 0.0;
            for (int k = l; k < 1024; k += 64) {
              unsigned u = ald(ahpk + (size_t)rowg * 1024 + k);
              float av = us2f((unsigned short)(u >> 16)) + us2f((unsigned short)(u & 0xffffu));
              s_ += (double)av * (double)Wout_f32[(size_t)k * 32000 + c];
            }
#pragma unroll
            for (int off = 32; off > 0; off >>= 1) s_ += __shfl_down(s_, off);
            if (l == 0) { rs[wv] = s_ + (double)b_op[c]; rc[wv] = c; }
          }
          __syncthreads();
          if (tid == 0) {
            double bv = -1e30; int bc = 0x7fffffff;
            for (int ci = 0; ci < cnt; ci++) {
              double s_ = rs[ci]; int c = rc[ci];
              if (s_ > bv || (s_ == bv && c < bc)) { bv = s_; bc = c; }
            }
            ast(ybuf + rowg, (unsigned)bc);
          }
        }
        bar64(barL, lgenL, lid); lgenL++;
        if (tid < 16) y_l[tid] = (int)ald(ybuf + bg * 16 + tid);
        __syncthreads();
        dec_lstmA(bg, cgl, tid, sm, hc, hn, dec_emb, KRh, KRl, dec_b, c_);
      }
    }
    bar64(barL, lgenL, lid); lgenL++;
    { unsigned* tp = hc; hc = hn; hn = tp; }
  }
}

// ---------------- host launch ----------------
extern "C" void kernel_launch(void* const* d_in, const int* in_sizes, int n_in,
                              void* d_out, int out_size, void* d_ws, size_t ws_size,
                              hipStream_t stream) {
  (void)in_sizes; (void)n_in; (void)out_size; (void)ws_size;
  const int*   src     = (const int*)  d_in[0];
  const float* enc_emb = (const float*)d_in[1];
  const float* enc_K   = (const float*)d_in[2];
  const float* enc_R   = (const float*)d_in[3];
  const float* enc_b   = (const float*)d_in[4];
  const float* dec_emb = (const float*)d_in[5];
  const float* dec_K   = (const float*)d_in[6];
  const float* dec_R   = (const float*)d_in[7];
  const float* dec_b   = (const float*)d_in[8];
  const float* W_a     = (const float*)d_in[9];
  const float* W_c     = (const float*)d_in[10];
  const float* b_c     = (const float*)d_in[11];
  const float* W_out   = (const float*)d_in[12];
  const float* b_out   = (const float*)d_in[13];
  char* ws = (char*)d_ws;

  hipFuncSetAttribute((const void*)ed_enc_vA, hipFuncAttributeMaxDynamicSharedMemorySize, 163840);
  hipFuncSetAttribute((const void*)ed_dec_vA, hipFuncAttributeMaxDynamicSharedMemorySize, 163840);

  bf16* KpTh = (bf16*)(ws + OKPT_H);
  bf16* KpTl = (bf16*)(ws + OKPT_L);
  bf16* RpTh = (bf16*)(ws + ORPT_H);
  bf16* RpTl = (bf16*)(ws + ORPT_L);
  bf16* xeh  = (bf16*)(ws + OXE_H);
  bf16* xel  = (bf16*)(ws + OXE_L);
  float* hsf = (float*)(ws + OHSF5);
  unsigned* hpkE0 = (unsigned*)(ws + OHPK_E0);
  unsigned* hpkE1 = (unsigned*)(ws + OHPK_E1);
  unsigned* hpkD0 = (unsigned*)(ws + OHPK_D0);
  float* cbuf = (float*)(ws + OCBUF5);
  unsigned* ahpk = (unsigned*)(ws + OAHPK);
  unsigned* ahb32 = (unsigned*)(ws + OAHB);
  float* rsum = (float*)(ws + ORSUM5);
  float* rmaxp = (float*)(ws + ORMAX5);
  int*  ridxp = (int*)(ws + ORIDX5);
  float* psum = (float*)(ws + OPSUM5);
  unsigned* barsE = (unsigned*)(ws + OBARS5);
  unsigned* barsG = (unsigned*)(ws + OBARS5 + 4096);
  unsigned* barsL = (unsigned*)(ws + OBARS5 + 8192);
  unsigned* ybuf = (unsigned*)(ws + OYBUF);
  bf16* XkL  = (bf16*)(ws + OXK_L5);
  bf16* XkH  = (bf16*)d_out;
  bf16* WcTh = (bf16*)(ws + OWCT_H);
  bf16* WcTl = (bf16*)(ws + OWCT_L);
  float* pctx = (float*)(ws + OPCTX5);
  float* qbuf = (float*)(ws + OQBUF);
  bf16* WaB  = (bf16*)(ws + OWAB);
  bf16* WoTh = (bf16*)(ws + OWOT5);
  bf16* KRTh = (bf16*)(ws + OKRTH5);
  bf16* KRTl = (bf16*)(ws + OKRTL5);

  ed_zero_vA<<<512, 256, 0, stream>>>((float4*)(ws + XCH), 131072);
  ed_transpose_split_vA<<<dim3(128, 32), 256, 0, stream>>>(enc_K, KpTh, KpTl, 1024, 4096, 1024, 0, 1);
  ed_transpose_split_vA<<<dim3(128, 32), 256, 0, stream>>>(enc_R, RpTh, RpTl, 1024, 4096, 1024, 0, 1);
  ed_gather_split_vA<<<16384, 256, 0, stream>>>(src, enc_emb, xeh, xel);
  ed_gemm3_vA<<<dim3(32, 128), 256, 0, stream>>>(xeh, xel, KpTh, KpTl, XkH, XkL, 16384, 4096, 1024);
  ed_transpose_split_vA<<<dim3(32, 64), 256, 0, stream>>>(W_c, WcTh, WcTl, 2048, 1024, 2048, 0, 0);
  ed_enc_vA<<<256, 1024, 87040, stream>>>(src, RpTh, RpTl, XkH, XkL, enc_b,
                                          hpkE0, hpkE1, cbuf, hsf, barsE);
  ed_cvt_vA<<<1024, 256, 0, stream>>>(W_a, WaB, 1048576);
  ed_transpose_vA<<<dim3(1000, 32), 256, 0, stream>>>(W_out, WoTh, 1024, 32000, 1024, 0, 0);
  ed_transpose_split_vA<<<dim3(128, 32), 256, 0, stream>>>(dec_K, KRTh, KRTl, 1024, 4096, 2048, 0, 1);
  ed_transpose_split_vA<<<dim3(128, 32), 256, 0, stream>>>(dec_R, KRTh, KRTl, 1024, 4096, 2048, 1024, 1);
  ed_dec_vA<<<256, 1024, 150528, stream>>>(src, KRTh, KRTl, dec_b, WcTh, WcTl, b_c,
                                           WoTh, b_out, W_out, dec_emb, WaB, qbuf, hsf,
                                           hpkE0, hpkD0, cbuf, pctx, psum, ahpk, ahb32,
                                           rsum, rmaxp, ridxp, ybuf, (float*)d_out,
                                           barsG, barsL);
}